// Round 14
// baseline (216.755 us; speedup 1.0000x reference)
//
#include <hip/hip_runtime.h>

#define NN 100000
#define NE 800000
#define NPB 512   // k_pool blocks
#define SRCMASK 0x01FFFFFF

typedef short bf16x8 __attribute__((ext_vector_type(8)));
typedef float f32x4 __attribute__((ext_vector_type(4)));
typedef int i32x4 __attribute__((ext_vector_type(4)));

__device__ __forceinline__ float wave_reduce_sum(float v) {
    #pragma unroll
    for (int o = 32; o > 0; o >>= 1) v += __shfl_down(v, o, 64);
    return v; // valid in lane 0
}

__device__ __forceinline__ unsigned short f2bf(float f) {
    unsigned u = __float_as_uint(f);
    unsigned r = (u + 0x7FFFu + ((u >> 16) & 1u)) >> 16;
    return (unsigned short)r;
}
__device__ __forceinline__ float bf2f(unsigned short b) {
    return __uint_as_float(((unsigned)b) << 16);
}
__device__ __forceinline__ float bflo(unsigned u) {   // low bf16 of u32
    return __uint_as_float(u << 16);
}
__device__ __forceinline__ float bfhi(unsigned u) {   // high bf16 of u32
    return __uint_as_float(u & 0xFFFF0000u);
}
__device__ __forceinline__ unsigned pk2(float a, float b) {
    return (unsigned)f2bf(a) | ((unsigned)f2bf(b) << 16);
}

// cb layout (floats): [0..27] vs1(k*4+h)  [28..55] vd1  [56..59] c1[h]  [60] c2
// W2fr: 5 col-tiles x 8 k-slices, B-fragment order; tile ct=4 col0=W2@as2, col1=W2@ad2
__global__ void k_pre(const float* __restrict__ W1, const float* __restrict__ as1,
                      const float* __restrict__ ad1,
                      const float* __restrict__ We1, const float* __restrict__ ae1,
                      const float* __restrict__ We2, const float* __restrict__ ae2,
                      const float* __restrict__ W2, const float* __restrict__ as2,
                      const float* __restrict__ ad2,
                      float* __restrict__ cb, unsigned short* __restrict__ W2fr) {
    int t = threadIdx.x;
    if (blockIdx.x == 0) {
        if (t < 28) {
            int k = t >> 2, h = t & 3;
            float s = 0.f, d = 0.f;
            for (int c = 0; c < 64; ++c) {
                float w = W1[k * 256 + h * 64 + c];
                s += w * as1[h * 64 + c];
                d += w * ad1[h * 64 + c];
            }
            cb[t] = s; cb[28 + t] = d;
        } else if (t < 32) {
            int h = t - 28;
            float s = 0.f;
            for (int c = 0; c < 64; ++c) s += We1[h * 64 + c] * ae1[h * 64 + c];
            cb[56 + h] = s;
        } else if (t == 32) {
            float s = 0.f;
            for (int c = 0; c < 64; ++c) s += We2[c] * ae2[c];
            cb[60] = s;
        }
    } else {
        int o = (blockIdx.x - 1) * 256 + t;        // 0..20479
        if (o >= 20480) return;
        int i = o & 7, l = (o >> 3) & 63, rest = o >> 9;
        int ct = rest % 5, ks = rest / 5;
        int k = ks * 32 + ((l >> 4) * 8) + i;
        int cl = l & 15;
        if (ct < 4) {
            W2fr[o] = f2bf(W2[k * 64 + ct * 16 + cl]);
        } else if (cl < 2) {
            const float* av = (cl == 0) ? as2 : ad2;
            float s = 0.f;
            for (int j = 0; j < 64; ++j) s += W2[k * 64 + j] * av[j];
            W2fr[o] = f2bf(s);
        } else {
            W2fr[o] = 0;
        }
    }
}

// per-node: packed bf16 attention record + packed bf16 x-record; fused dst histogram
__global__ void k_node1h(const float* __restrict__ x, const float* __restrict__ cb,
                         const int* __restrict__ dst,
                         uint4* __restrict__ anode, uint4* __restrict__ xpack,
                         int* __restrict__ hist) {
    int n = blockIdx.x * 256 + threadIdx.x;
    if (n >= NN) return;
    float xv[7];
    #pragma unroll
    for (int k = 0; k < 7; ++k) xv[k] = x[n * 7 + k];
    float s[4] = {0.f, 0.f, 0.f, 0.f}, d[4] = {0.f, 0.f, 0.f, 0.f};
    #pragma unroll
    for (int k = 0; k < 7; ++k)
        #pragma unroll
        for (int h = 0; h < 4; ++h) {
            s[h] += xv[k] * cb[k * 4 + h];
            d[h] += xv[k] * cb[28 + k * 4 + h];
        }
    anode[n] = make_uint4(pk2(s[0], s[1]), pk2(s[2], s[3]), pk2(d[0], d[1]), pk2(d[2], d[3]));
    xpack[n] = make_uint4(pk2(xv[0], xv[1]), pk2(xv[2], xv[3]),
                          pk2(xv[4], xv[5]), pk2(xv[6], 1.f));
    // histogram: edges [n*8, n*8+8)
    int e0 = n * 8;
    int4 d0 = *(const int4*)(dst + e0);
    int4 d1 = *(const int4*)(dst + e0 + 4);
    atomicAdd(&hist[d0.x], 1); atomicAdd(&hist[d0.y], 1);
    atomicAdd(&hist[d0.z], 1); atomicAdd(&hist[d0.w], 1);
    atomicAdd(&hist[d1.x], 1); atomicAdd(&hist[d1.y], 1);
    atomicAdd(&hist[d1.z], 1); atomicAdd(&hist[d1.w], 1);
}

// --- 3-phase parallel exclusive scan over hist[NN] -> offs[NN+1], cursor[NN] ---
__global__ __launch_bounds__(1024) void k_scanA(const int* __restrict__ hist,
                                                int* __restrict__ bsum) {
    __shared__ int ws[16];
    int i = blockIdx.x * 1024 + threadIdx.x;
    int lane = threadIdx.x & 63, wid = threadIdx.x >> 6;
    int v = (i < NN) ? hist[i] : 0;
    #pragma unroll
    for (int o = 32; o; o >>= 1) v += __shfl_down(v, o, 64);
    if (lane == 0) ws[wid] = v;
    __syncthreads();
    if (wid == 0) {
        int u = (lane < 16) ? ws[lane] : 0;
        #pragma unroll
        for (int o = 8; o; o >>= 1) u += __shfl_down(u, o, 64);
        if (lane == 0) bsum[blockIdx.x] = u;
    }
}

__global__ void k_scanB(const int* __restrict__ bsum, int* __restrict__ bexcl) {
    __shared__ int w0tot;
    int t = threadIdx.x, lane = t & 63, wid = t >> 6;
    int v = (t < 98) ? bsum[t] : 0;
    int s = v;
    #pragma unroll
    for (int d = 1; d < 64; d <<= 1) { int u = __shfl_up(s, d, 64); if (lane >= d) s += u; }
    if (t == 63) w0tot = s;
    __syncthreads();
    if (wid == 1) s += w0tot;
    if (t < 98) bexcl[t] = s - v;
}

__global__ __launch_bounds__(1024) void k_scanC(const int* __restrict__ hist,
                                                const int* __restrict__ bexcl,
                                                int* __restrict__ offs,
                                                int* __restrict__ cursor) {
    __shared__ int ws[16];
    int b = blockIdx.x;
    int i = b * 1024 + threadIdx.x;
    int lane = threadIdx.x & 63, wid = threadIdx.x >> 6;
    int v = (i < NN) ? hist[i] : 0;
    int s = v;
    #pragma unroll
    for (int d = 1; d < 64; d <<= 1) { int u = __shfl_up(s, d, 64); if (lane >= d) s += u; }
    if (lane == 63) ws[wid] = s;
    __syncthreads();
    if (wid == 0) {
        int u2 = (lane < 16) ? ws[lane] : 0;
        #pragma unroll
        for (int d = 1; d < 16; d <<= 1) { int uu = __shfl_up(u2, d, 64); if (lane >= d) u2 += uu; }
        if (lane < 16) ws[lane] = u2;
    }
    __syncthreads();
    int incl = s + (wid ? ws[wid - 1] : 0) + bexcl[b];
    if (i < NN) { offs[i + 1] = incl; cursor[i] = incl - v; }
    if (i == 0) offs[0] = 0;
}

// scatter + conv1 edge weights via packed anode records; nontemporal 16B store
__global__ void k_scatter(const int* __restrict__ src, const int* __restrict__ dst,
                          const float* __restrict__ ea,
                          const uint4* __restrict__ anode, const float* __restrict__ cb,
                          int* __restrict__ cursor, int4* __restrict__ es2) {
    int e = blockIdx.x * 256 + threadIdx.x;
    if (e >= NE) return;
    int s = src[e], d = dst[e];
    float eav = ea[e];
    int pos = atomicAdd(&cursor[d], 1);
    uint4 ar = anode[s];
    uint4 br = anode[d];
    float lg0 = bflo(ar.x) + bflo(br.z) + eav * cb[56];
    float lg1 = bfhi(ar.x) + bfhi(br.z) + eav * cb[57];
    float lg2 = bflo(ar.y) + bflo(br.w) + eav * cb[58];
    float lg3 = bfhi(ar.y) + bfhi(br.w) + eav * cb[59];
    lg0 = lg0 >= 0.f ? lg0 : 0.2f * lg0;
    lg1 = lg1 >= 0.f ? lg1 : 0.2f * lg1;
    lg2 = lg2 >= 0.f ? lg2 : 0.2f * lg2;
    lg3 = lg3 >= 0.f ? lg3 : 0.2f * lg3;
    unsigned w01 = pk2(__expf(lg0), __expf(lg1));
    unsigned w23 = pk2(__expf(lg2), __expf(lg3));
    i32x4 rec = {(int)w01, (int)w23, s | ((d & 31) << 25), __float_as_int(eav)};
    __builtin_nontemporal_store(rec, (i32x4*)&es2[pos]);
}

// fused conv1: packed-LDS two-phase segmented reduce -> h -> MFMA
// 5th col-tile computes a_src2/a_dst2 directly (no shfl epilogue)
__global__ __launch_bounds__(256, 7) void k_conv1red(
    const uint4* __restrict__ xpack, const float* __restrict__ W1, const float* __restrict__ b1,
    const int* __restrict__ offs, const int4* __restrict__ es2,
    const unsigned short* __restrict__ W2fr,
    unsigned short* __restrict__ xh2b, float* __restrict__ a_src2, float* __restrict__ a_dst2) {
    // overlay: xs/wsx (phases 1-2) share storage with hs (finish/MFMA phases)
    __shared__ __attribute__((aligned(16))) unsigned char smem[16896];
    uint4* xs = (uint4*)smem;                                   // [256] 4096 B
    uint2* wsx = (uint2*)(smem + 4096);                         // [256] 2048 B
    typedef unsigned short hsrow[264];
    hsrow* hs = (hsrow*)smem;                                   // [32][264] 16896 B
    __shared__ int soffs[33];
    __shared__ float ms[32][33];
    int t = threadIdx.x, lane = t & 63, wid = t >> 6;
    int n0 = blockIdx.x * 32;
    if (t <= 32) soffs[t] = offs[n0 + t];
    float w1r[7][4], b1r[4];
    #pragma unroll
    for (int k = 0; k < 7; ++k)
        #pragma unroll
        for (int h = 0; h < 4; ++h) w1r[k][h] = W1[k * 256 + h * 64 + lane];
    #pragma unroll
    for (int h = 0; h < 4; ++h) b1r[h] = b1[h * 64 + lane];
    __syncthreads();
    int E0 = soffs[0], E1 = soffs[32];
    int g = t >> 3, q = t & 7;
    int go0 = soffs[g], go1 = soffs[g + 1];
    int qh = q >> 1;
    int xsl = (q & 1) ? 0 : 16;    // shift to put selected bf16 in high half
    float mh0 = 0.f, mh1 = 0.f, mh2 = 0.f, mh3 = 0.f;
    for (int C0 = E0; C0 < E1; C0 += 256) {
        int C1 = min(C0 + 256, E1);
        int j = C0 + t;
        if (j < C1) {
            int4 e4 = es2[j];
            xs[t] = xpack[e4.z & SRCMASK];
            wsx[t] = make_uint2((unsigned)e4.x, (unsigned)e4.y);
        }
        __syncthreads();
        int lo = max(go0, C0) - C0, hi = min(go1, C1) - C0;
        for (int jj = lo; jj < hi; ++jj) {
            unsigned xu = ((const unsigned*)&xs[jj])[qh];
            float xv = __uint_as_float((xu << xsl) & 0xFFFF0000u);
            uint2 wv = wsx[jj];
            mh0 = fmaf(bflo(wv.x), xv, mh0);
            mh1 = fmaf(bfhi(wv.x), xv, mh1);
            mh2 = fmaf(bflo(wv.y), xv, mh2);
            mh3 = fmaf(bfhi(wv.y), xv, mh3);
        }
        __syncthreads();
    }
    ms[g][0 * 8 + q] = mh0; ms[g][1 * 8 + q] = mh1;
    ms[g][2 * 8 + q] = mh2; ms[g][3 * 8 + q] = mh3;
    __syncthreads();          // xs/wsx dead from here; hs may now overwrite
    // finish: 8 nodes per wave, lane = channel
    for (int gi = wid * 8; gi < wid * 8 + 8; ++gi) {
        bool has = soffs[gi + 1] > soffs[gi];
        #pragma unroll
        for (int h = 0; h < 4; ++h) {
            float rz = __builtin_amdgcn_rcpf(ms[gi][h * 8 + 7]);
            float a = 0.f;
            #pragma unroll
            for (int k = 0; k < 7; ++k) a = fmaf(ms[gi][h * 8 + k], w1r[k][h], a);
            float mm = (has ? a * rz : 0.f) + b1r[h];
            float hv = mm > 0.f ? mm : (__expf(mm) - 1.f);
            hs[gi][h * 64 + lane] = f2bf(hv);
        }
    }
    __syncthreads();
    // MFMA: 2 node-tiles x 5 col-tiles (ct=4 -> a_src2/a_dst2 columns)
    int row = lane & 15, kg = lane >> 4;
    #pragma unroll
    for (int u = wid; u < 10; u += 4) {
        int nt = u & 1, ct = u >> 1;
        f32x4 acc = {0.f, 0.f, 0.f, 0.f};
        #pragma unroll
        for (int ks = 0; ks < 8; ++ks) {
            bf16x8 av = *(const bf16x8*)&hs[nt * 16 + row][ks * 32 + kg * 8];
            bf16x8 bv = *(const bf16x8*)(W2fr + (((ks * 5 + ct) * 64) + lane) * 8);
            acc = __builtin_amdgcn_mfma_f32_16x16x32_bf16(av, bv, acc, 0, 0, 0);
        }
        if (ct < 4) {
            #pragma unroll
            for (int i = 0; i < 4; ++i)
                xh2b[(n0 + nt * 16 + kg * 4 + i) * 64 + ct * 16 + row] = f2bf(acc[i]);
        } else if (row == 0) {
            #pragma unroll
            for (int i = 0; i < 4; ++i) a_src2[n0 + nt * 16 + kg * 4 + i] = acc[i];
        } else if (row == 1) {
            #pragma unroll
            for (int i = 0; i < 4; ++i) a_dst2[n0 + nt * 16 + kg * 4 + i] = acc[i];
        }
    }
}

// conv2 normalization: single-read, register-carried (2 edges/thread covers span<=512;
// rare overflow handled via LDS z atomics + re-read)
__global__ __launch_bounds__(256) void k_znorm(
    const int4* __restrict__ es2, const int* __restrict__ offs,
    const float* __restrict__ a_src2, const float* __restrict__ a_dst2,
    const int* __restrict__ assign, const float* __restrict__ cb,
    float* __restrict__ cs) {
    __shared__ int soffs[33];
    __shared__ float adL[32];
    __shared__ int asgL[32];
    __shared__ float ewL[512];
    __shared__ float rzL[32];
    __shared__ float zacc[32];
    int t = threadIdx.x;
    int n0 = blockIdx.x * 32;
    if (t <= 32) soffs[t] = offs[n0 + t];
    if (t < 32) { adL[t] = a_dst2[n0 + t]; asgL[t] = assign[n0 + t]; zacc[t] = 0.f; }
    __syncthreads();
    int E0 = soffs[0], E1 = soffs[32];
    float c2 = cb[60];
    // register-carried edges (slots t and 256+t)
    int sx0 = 0, d50 = 0, sx1 = 0, d51 = 0;
    float ew0 = 0.f, ew1 = 0.f;
    bool h0 = (E0 + t) < E1, h1 = (E0 + 256 + t) < E1;
    if (h0) {
        int4 e4 = es2[E0 + t];
        sx0 = e4.z & SRCMASK; d50 = (e4.z >> 25) & 31;
        float lg = a_src2[sx0] + adL[d50] + __int_as_float(e4.w) * c2;
        lg = lg >= 0.f ? lg : 0.2f * lg;
        ew0 = __expf(lg);
        ewL[t] = ew0;
    }
    if (h1) {
        int4 e4 = es2[E0 + 256 + t];
        sx1 = e4.z & SRCMASK; d51 = (e4.z >> 25) & 31;
        float lg = a_src2[sx1] + adL[d51] + __int_as_float(e4.w) * c2;
        lg = lg >= 0.f ? lg : 0.2f * lg;
        ew1 = __expf(lg);
        ewL[256 + t] = ew1;
    }
    // rare overflow edges: accumulate z via LDS atomics
    for (int j = E0 + 512 + t; j < E1; j += 256) {
        int4 e4 = es2[j];
        int d5 = (e4.z >> 25) & 31;
        float lg = a_src2[e4.z & SRCMASK] + adL[d5] + __int_as_float(e4.w) * c2;
        lg = lg >= 0.f ? lg : 0.2f * lg;
        atomicAdd(&zacc[d5], __expf(lg));
    }
    __syncthreads();
    // per-node z from ewL (8 lanes per node)
    int g = t >> 3, q = t & 7;
    int lo = soffs[g] - E0, hi = min(soffs[g + 1] - E0, 512);
    float z = 0.f;
    for (int jj = lo + q; jj < hi; jj += 8) z += ewL[jj];
    z += __shfl_xor(z, 1, 64);
    z += __shfl_xor(z, 2, 64);
    z += __shfl_xor(z, 4, 64);
    if (q == 0) rzL[g] = __builtin_amdgcn_rcpf(z + zacc[g]);
    __syncthreads();
    // pass 2 from registers
    if (h0) atomicAdd(&cs[sx0 * 4 + asgL[d50]], ew0 * rzL[d50]);
    if (h1) atomicAdd(&cs[sx1 * 4 + asgL[d51]], ew1 * rzL[d51]);
    for (int j = E0 + 512 + t; j < E1; j += 256) {
        int4 e4 = es2[j];
        int sx = e4.z & SRCMASK, d5 = (e4.z >> 25) & 31;
        float lg = a_src2[sx] + adL[d5] + __int_as_float(e4.w) * c2;
        lg = lg >= 0.f ? lg : 0.2f * lg;
        atomicAdd(&cs[sx * 4 + asgL[d5]], __expf(lg) * rzL[d5]);
    }
}

// pooling as tiny GEMM: 8 lanes/node, 16B loads, register accumulators, direct gacc atomics
__global__ __launch_bounds__(256) void k_pool(
    const unsigned short* __restrict__ xh2b, const float* __restrict__ cs,
    const int* __restrict__ assign, const float* __restrict__ x,
    float* __restrict__ gacc) {
    __shared__ float csum[264];
    int t = threadIdx.x;
    int q = t & 7, slot = t >> 3;             // 32 node-slots per block
    float a0[8], a1[8], a2[8], a3[8];
    #pragma unroll
    for (int j = 0; j < 8; ++j) { a0[j] = 0.f; a1[j] = 0.f; a2[j] = 0.f; a3[j] = 0.f; }
    float cnt0 = 0.f, cnt1 = 0.f, cnt2 = 0.f, cnt3 = 0.f;
    float cf0 = 0.f, cf1 = 0.f, cf2 = 0.f, cf3 = 0.f;
    for (int n = blockIdx.x * 32 + slot; n < NN; n += NPB * 32) {
        uint4 u = *(const uint4*)(xh2b + n * 64 + q * 8);
        float4 c4 = *(const float4*)(cs + n * 4);
        float xv[8];
        xv[0] = bf2f((unsigned short)u.x); xv[1] = bf2f((unsigned short)(u.x >> 16));
        xv[2] = bf2f((unsigned short)u.y); xv[3] = bf2f((unsigned short)(u.y >> 16));
        xv[4] = bf2f((unsigned short)u.z); xv[5] = bf2f((unsigned short)(u.z >> 16));
        xv[6] = bf2f((unsigned short)u.w); xv[7] = bf2f((unsigned short)(u.w >> 16));
        #pragma unroll
        for (int j = 0; j < 8; ++j) {
            a0[j] = fmaf(c4.x, xv[j], a0[j]);
            a1[j] = fmaf(c4.y, xv[j], a1[j]);
            a2[j] = fmaf(c4.z, xv[j], a2[j]);
            a3[j] = fmaf(c4.w, xv[j], a3[j]);
        }
        if (q == 0) {
            int a = assign[n];
            float xf = x[n * 7 + 6];
            cnt0 += (a == 0) ? 1.f : 0.f;  cf0 += (a == 0) ? xf : 0.f;
            cnt1 += (a == 1) ? 1.f : 0.f;  cf1 += (a == 1) ? xf : 0.f;
            cnt2 += (a == 2) ? 1.f : 0.f;  cf2 += (a == 2) ? xf : 0.f;
            cnt3 += (a == 3) ? 1.f : 0.f;  cf3 += (a == 3) ? xf : 0.f;
        }
    }
    for (int i = t; i < 264; i += 256) csum[i] = 0.f;
    __syncthreads();
    int base = q * 8;
    #pragma unroll
    for (int j = 0; j < 8; ++j) {
        atomicAdd(&csum[0 * 64 + base + j], a0[j]);
        atomicAdd(&csum[1 * 64 + base + j], a1[j]);
        atomicAdd(&csum[2 * 64 + base + j], a2[j]);
        atomicAdd(&csum[3 * 64 + base + j], a3[j]);
    }
    if (q == 0) {
        atomicAdd(&csum[256], cnt0); atomicAdd(&csum[257], cnt1);
        atomicAdd(&csum[258], cnt2); atomicAdd(&csum[259], cnt3);
        atomicAdd(&csum[260], cf0);  atomicAdd(&csum[261], cf1);
        atomicAdd(&csum[262], cf2);  atomicAdd(&csum[263], cf3);
    }
    __syncthreads();
    for (int i = t; i < 264; i += 256) atomicAdd(&gacc[i], csum[i]);
}

// final head (256 threads): cluster means (+cnt*b2), actor MLP + softmax, critic MLP
__global__ __launch_bounds__(256) void k_head(
    const float* __restrict__ gacc, const float* __restrict__ b2,
    const float* __restrict__ A1, const float* __restrict__ ba1,
    const float* __restrict__ A2, const float* __restrict__ ba2,
    const float* __restrict__ C1, const float* __restrict__ bc1,
    const float* __restrict__ C2, const float* __restrict__ bc2,
    float* __restrict__ out) {
    __shared__ float zc[4][64];
    __shared__ float cfs[4];
    __shared__ float logits[4];
    __shared__ float vpart[4][64];
    int t = threadIdx.x;
    int j = t & 63, wv = t >> 6;   // wave wv handles cluster wv
    float cnt = gacc[256 + wv];
    float den = fmaxf(cnt, 1.f);
    zc[wv][j] = (cnt > 0.f) ? (gacc[wv * 64 + j] + cnt * b2[j]) / den : 0.f;
    if (t < 4) {
        float cc = gacc[256 + t];
        cfs[t] = (cc > 0.f) ? gacc[260 + t] / fmaxf(cc, 1.f) : 0.f;
    }
    __syncthreads();
    // actor: cluster wv
    float tv = ba1[j];
    for (int k = 0; k < 64; ++k) tv = fmaf(zc[wv][k], A1[k * 64 + j], tv);
    tv = fmaf(cfs[wv], A1[64 * 64 + j], tv);
    tv = fmaxf(tv, 0.f);
    float sred = wave_reduce_sum(tv * A2[j]);
    if (j == 0) logits[wv] = sred + ba2[0];
    // critic partials: wave wv covers k in [wv*64, (wv+1)*64)
    float vj = (wv == 0) ? bc1[j] : 0.f;
    for (int kk = 0; kk < 64; ++kk) vj = fmaf(zc[wv][kk], C1[(wv * 64 + kk) * 64 + j], vj);
    vpart[wv][j] = vj;
    __syncthreads();
    if (wv == 0) {
        float vv = fmaxf(vpart[0][j] + vpart[1][j] + vpart[2][j] + vpart[3][j], 0.f);
        float v = wave_reduce_sum(vv * C2[j]);
        if (j == 0) {
            float m = fmaxf(fmaxf(logits[0], logits[1]), fmaxf(logits[2], logits[3]));
            float e0 = __expf(logits[0] - m), e1 = __expf(logits[1] - m);
            float e2 = __expf(logits[2] - m), e3 = __expf(logits[3] - m);
            float sum = e0 + e1 + e2 + e3;
            out[0] = e0 / sum; out[1] = e1 / sum; out[2] = e2 / sum; out[3] = e3 / sum;
            out[4] = v + bc2[0];
        }
    }
    out[5 + wv * 64 + j] = zc[wv][j];
}

extern "C" void kernel_launch(void* const* d_in, const int* in_sizes, int n_in,
                              void* d_out, int out_size, void* d_ws, size_t ws_size,
                              hipStream_t stream) {
    const float* x    = (const float*)d_in[0];
    const int*   ei   = (const int*)d_in[1];
    const float* ea   = (const float*)d_in[2];
    const int*   asg  = (const int*)d_in[3];
    const float* W1   = (const float*)d_in[4];
    const float* as1  = (const float*)d_in[5];
    const float* ad1  = (const float*)d_in[6];
    const float* We1  = (const float*)d_in[7];
    const float* ae1  = (const float*)d_in[8];
    const float* b1   = (const float*)d_in[9];
    const float* W2   = (const float*)d_in[10];
    const float* as2  = (const float*)d_in[11];
    const float* ad2  = (const float*)d_in[12];
    const float* We2  = (const float*)d_in[13];
    const float* ae2  = (const float*)d_in[14];
    const float* b2   = (const float*)d_in[15];
    const float* A1   = (const float*)d_in[16];
    const float* ba1  = (const float*)d_in[17];
    const float* A2   = (const float*)d_in[18];
    const float* ba2  = (const float*)d_in[19];
    const float* C1   = (const float*)d_in[20];
    const float* bc1  = (const float*)d_in[21];
    const float* C2   = (const float*)d_in[22];
    const float* bc2  = (const float*)d_in[23];
    const int* src = ei;
    const int* dst = ei + NE;

    char* w = (char*)d_ws;
    size_t off = 0;
    auto alloc = [&](size_t bytes) -> void* {
        void* p = w + off;
        off += (bytes + 255) & ~(size_t)255;
        return p;
    };
    // contiguous zero-init region: hist | cs | gacc
    int*   hist   = (int*)alloc(NN * sizeof(int));
    float* cs     = (float*)alloc(NN * 4 * sizeof(float));
    float* gacc   = (float*)alloc(264 * sizeof(float));
    size_t zspan  = (size_t)((char*)gacc + 264 * sizeof(float) - (char*)hist);
    uint4* anode  = (uint4*)alloc(NN * sizeof(uint4));
    float* a_src2 = (float*)alloc(NN * sizeof(float));
    float* a_dst2 = (float*)alloc(NN * sizeof(float));
    uint4* xpack  = (uint4*)alloc(NN * sizeof(uint4));
    int*   offs   = (int*)alloc((NN + 1) * sizeof(int));
    int*   cursor = (int*)alloc(NN * sizeof(int));
    int*   bsum   = (int*)alloc(128 * sizeof(int));
    int*   bexcl  = (int*)alloc(128 * sizeof(int));
    int4*  es2    = (int4*)alloc(NE * sizeof(int4));
    unsigned short* xh2b = (unsigned short*)alloc(NN * 64 * sizeof(unsigned short));
    unsigned short* W2fr = (unsigned short*)alloc(20480 * sizeof(unsigned short));
    float* cb     = (float*)alloc(64 * sizeof(float));
    (void)ws_size; (void)n_in; (void)in_sizes; (void)out_size;

    (void)hipMemsetAsync(hist, 0, zspan, stream);

    k_pre<<<81, 256, 0, stream>>>(W1, as1, ad1, We1, ae1, We2, ae2, W2, as2, ad2, cb, W2fr);
    k_node1h<<<(NN + 255) / 256, 256, 0, stream>>>(x, cb, dst, anode, xpack, hist);
    k_scanA<<<98, 1024, 0, stream>>>(hist, bsum);
    k_scanB<<<1, 128, 0, stream>>>(bsum, bexcl);
    k_scanC<<<98, 1024, 0, stream>>>(hist, bexcl, offs, cursor);
    k_scatter<<<(NE + 255) / 256, 256, 0, stream>>>(src, dst, ea, anode, cb, cursor, es2);
    k_conv1red<<<NN / 32, 256, 0, stream>>>(xpack, W1, b1, offs, es2,
                                            W2fr, xh2b, a_src2, a_dst2);
    k_znorm<<<NN / 32, 256, 0, stream>>>(es2, offs, a_src2, a_dst2, asg, cb, cs);
    k_pool<<<NPB, 256, 0, stream>>>(xh2b, cs, asg, x, gacc);
    k_head<<<1, 256, 0, stream>>>(gacc, b2, A1, ba1, A2, ba2, C1, bc1, C2, bc2, (float*)d_out);
}

// Round 15
// 192.299 us; speedup vs baseline: 1.1272x; 1.1272x over previous
//
#include <hip/hip_runtime.h>

#define NN 100000
#define NE 800000
#define NPB 512   // k_pool blocks
#define SRCMASK 0x01FFFFFF

typedef short bf16x8 __attribute__((ext_vector_type(8)));
typedef float f32x4 __attribute__((ext_vector_type(4)));

__device__ __forceinline__ float wave_reduce_sum(float v) {
    #pragma unroll
    for (int o = 32; o > 0; o >>= 1) v += __shfl_down(v, o, 64);
    return v; // valid in lane 0
}

__device__ __forceinline__ unsigned short f2bf(float f) {
    unsigned u = __float_as_uint(f);
    unsigned r = (u + 0x7FFFu + ((u >> 16) & 1u)) >> 16;
    return (unsigned short)r;
}
__device__ __forceinline__ float bf2f(unsigned short b) {
    return __uint_as_float(((unsigned)b) << 16);
}
__device__ __forceinline__ float bflo(unsigned u) {   // low bf16 of u32
    return __uint_as_float(u << 16);
}
__device__ __forceinline__ float bfhi(unsigned u) {   // high bf16 of u32
    return __uint_as_float(u & 0xFFFF0000u);
}
__device__ __forceinline__ unsigned pk2(float a, float b) {
    return (unsigned)f2bf(a) | ((unsigned)f2bf(b) << 16);
}

// cb layout (floats): [0..27] vs1(k*4+h)  [28..55] vd1  [56..59] c1[h]  [60] c2
// W2fr: 5 col-tiles x 8 k-slices, B-fragment order; tile ct=4 col0=W2@as2, col1=W2@ad2
__global__ void k_pre(const float* __restrict__ W1, const float* __restrict__ as1,
                      const float* __restrict__ ad1,
                      const float* __restrict__ We1, const float* __restrict__ ae1,
                      const float* __restrict__ We2, const float* __restrict__ ae2,
                      const float* __restrict__ W2, const float* __restrict__ as2,
                      const float* __restrict__ ad2,
                      float* __restrict__ cb, unsigned short* __restrict__ W2fr) {
    int t = threadIdx.x;
    if (blockIdx.x == 0) {
        if (t < 28) {
            int k = t >> 2, h = t & 3;
            float s = 0.f, d = 0.f;
            for (int c = 0; c < 64; ++c) {
                float w = W1[k * 256 + h * 64 + c];
                s += w * as1[h * 64 + c];
                d += w * ad1[h * 64 + c];
            }
            cb[t] = s; cb[28 + t] = d;
        } else if (t < 32) {
            int h = t - 28;
            float s = 0.f;
            for (int c = 0; c < 64; ++c) s += We1[h * 64 + c] * ae1[h * 64 + c];
            cb[56 + h] = s;
        } else if (t == 32) {
            float s = 0.f;
            for (int c = 0; c < 64; ++c) s += We2[c] * ae2[c];
            cb[60] = s;
        }
    } else {
        int o = (blockIdx.x - 1) * 256 + t;        // 0..20479
        if (o >= 20480) return;
        int i = o & 7, l = (o >> 3) & 63, rest = o >> 9;
        int ct = rest % 5, ks = rest / 5;
        int k = ks * 32 + ((l >> 4) * 8) + i;
        int cl = l & 15;
        if (ct < 4) {
            W2fr[o] = f2bf(W2[k * 64 + ct * 16 + cl]);
        } else if (cl < 2) {
            const float* av = (cl == 0) ? as2 : ad2;
            float s = 0.f;
            for (int j = 0; j < 64; ++j) s += W2[k * 64 + j] * av[j];
            W2fr[o] = f2bf(s);
        } else {
            W2fr[o] = 0;
        }
    }
}

// per-node: packed bf16 attention record + packed bf16 x-record;
// fused dst histogram capturing per-edge rank (coalesced int4 stores)
__global__ void k_node1h(const float* __restrict__ x, const float* __restrict__ cb,
                         const int* __restrict__ dst,
                         uint4* __restrict__ anode, uint4* __restrict__ xpack,
                         int* __restrict__ hist, int* __restrict__ rank) {
    int n = blockIdx.x * 256 + threadIdx.x;
    if (n >= NN) return;
    float xv[7];
    #pragma unroll
    for (int k = 0; k < 7; ++k) xv[k] = x[n * 7 + k];
    float s[4] = {0.f, 0.f, 0.f, 0.f}, d[4] = {0.f, 0.f, 0.f, 0.f};
    #pragma unroll
    for (int k = 0; k < 7; ++k)
        #pragma unroll
        for (int h = 0; h < 4; ++h) {
            s[h] += xv[k] * cb[k * 4 + h];
            d[h] += xv[k] * cb[28 + k * 4 + h];
        }
    anode[n] = make_uint4(pk2(s[0], s[1]), pk2(s[2], s[3]), pk2(d[0], d[1]), pk2(d[2], d[3]));
    xpack[n] = make_uint4(pk2(xv[0], xv[1]), pk2(xv[2], xv[3]),
                          pk2(xv[4], xv[5]), pk2(xv[6], 1.f));
    // histogram + rank: edges [n*8, n*8+8)
    int e0 = n * 8;
    int4 d0 = *(const int4*)(dst + e0);
    int4 d1 = *(const int4*)(dst + e0 + 4);
    int4 r0, r1;
    r0.x = atomicAdd(&hist[d0.x], 1); r0.y = atomicAdd(&hist[d0.y], 1);
    r0.z = atomicAdd(&hist[d0.z], 1); r0.w = atomicAdd(&hist[d0.w], 1);
    r1.x = atomicAdd(&hist[d1.x], 1); r1.y = atomicAdd(&hist[d1.y], 1);
    r1.z = atomicAdd(&hist[d1.z], 1); r1.w = atomicAdd(&hist[d1.w], 1);
    *(int4*)(rank + e0) = r0;
    *(int4*)(rank + e0 + 4) = r1;
}

// --- 3-phase parallel exclusive scan over hist[NN] -> offs[NN+1] ---
__global__ __launch_bounds__(1024) void k_scanA(const int* __restrict__ hist,
                                                int* __restrict__ bsum) {
    __shared__ int ws[16];
    int i = blockIdx.x * 1024 + threadIdx.x;
    int lane = threadIdx.x & 63, wid = threadIdx.x >> 6;
    int v = (i < NN) ? hist[i] : 0;
    #pragma unroll
    for (int o = 32; o; o >>= 1) v += __shfl_down(v, o, 64);
    if (lane == 0) ws[wid] = v;
    __syncthreads();
    if (wid == 0) {
        int u = (lane < 16) ? ws[lane] : 0;
        #pragma unroll
        for (int o = 8; o; o >>= 1) u += __shfl_down(u, o, 64);
        if (lane == 0) bsum[blockIdx.x] = u;
    }
}

__global__ void k_scanB(const int* __restrict__ bsum, int* __restrict__ bexcl) {
    __shared__ int w0tot;
    int t = threadIdx.x, lane = t & 63, wid = t >> 6;
    int v = (t < 98) ? bsum[t] : 0;
    int s = v;
    #pragma unroll
    for (int d = 1; d < 64; d <<= 1) { int u = __shfl_up(s, d, 64); if (lane >= d) s += u; }
    if (t == 63) w0tot = s;
    __syncthreads();
    if (wid == 1) s += w0tot;
    if (t < 98) bexcl[t] = s - v;
}

__global__ __launch_bounds__(1024) void k_scanC(const int* __restrict__ hist,
                                                const int* __restrict__ bexcl,
                                                int* __restrict__ offs) {
    __shared__ int ws[16];
    int b = blockIdx.x;
    int i = b * 1024 + threadIdx.x;
    int lane = threadIdx.x & 63, wid = threadIdx.x >> 6;
    int v = (i < NN) ? hist[i] : 0;
    int s = v;
    #pragma unroll
    for (int d = 1; d < 64; d <<= 1) { int u = __shfl_up(s, d, 64); if (lane >= d) s += u; }
    if (lane == 63) ws[wid] = s;
    __syncthreads();
    if (wid == 0) {
        int u2 = (lane < 16) ? ws[lane] : 0;
        #pragma unroll
        for (int d = 1; d < 16; d <<= 1) { int uu = __shfl_up(u2, d, 64); if (lane >= d) u2 += uu; }
        if (lane < 16) ws[lane] = u2;
    }
    __syncthreads();
    int incl = s + (wid ? ws[wid - 1] : 0) + bexcl[b];
    if (i < NN) offs[i + 1] = incl;
    if (i == 0) offs[0] = 0;
}

// scatter + conv1 edge weights; atomic-free (pos = offs[dst] + rank); 2 edges/thread
__global__ void k_scatter(const int* __restrict__ src, const int* __restrict__ dst,
                          const float* __restrict__ ea, const int* __restrict__ rank,
                          const int* __restrict__ offs,
                          const uint4* __restrict__ anode, const float* __restrict__ cb,
                          int4* __restrict__ es2) {
    int e0 = (blockIdx.x * 256 + threadIdx.x) * 2;
    if (e0 >= NE) return;
    int2 s2 = *(const int2*)(src + e0);
    int2 d2 = *(const int2*)(dst + e0);
    float2 a2 = *(const float2*)(ea + e0);
    int2 r2 = *(const int2*)(rank + e0);
    float c56 = cb[56], c57 = cb[57], c58 = cb[58], c59 = cb[59];
    #pragma unroll
    for (int u = 0; u < 2; ++u) {
        int s = u ? s2.y : s2.x;
        int d = u ? d2.y : d2.x;
        float eav = u ? a2.y : a2.x;
        int pos = offs[d] + (u ? r2.y : r2.x);
        uint4 ar = anode[s];
        uint4 br = anode[d];
        float lg0 = bflo(ar.x) + bflo(br.z) + eav * c56;
        float lg1 = bfhi(ar.x) + bfhi(br.z) + eav * c57;
        float lg2 = bflo(ar.y) + bflo(br.w) + eav * c58;
        float lg3 = bfhi(ar.y) + bfhi(br.w) + eav * c59;
        lg0 = lg0 >= 0.f ? lg0 : 0.2f * lg0;
        lg1 = lg1 >= 0.f ? lg1 : 0.2f * lg1;
        lg2 = lg2 >= 0.f ? lg2 : 0.2f * lg2;
        lg3 = lg3 >= 0.f ? lg3 : 0.2f * lg3;
        unsigned w01 = pk2(__expf(lg0), __expf(lg1));
        unsigned w23 = pk2(__expf(lg2), __expf(lg3));
        es2[pos] = make_int4((int)w01, (int)w23, s | ((d & 31) << 25), __float_as_int(eav));
    }
}

// fused conv1: packed-LDS two-phase segmented reduce -> h -> MFMA
// 5th col-tile computes a_src2/a_dst2 directly (no shfl epilogue)
__global__ __launch_bounds__(256, 7) void k_conv1red(
    const uint4* __restrict__ xpack, const float* __restrict__ W1, const float* __restrict__ b1,
    const int* __restrict__ offs, const int4* __restrict__ es2,
    const unsigned short* __restrict__ W2fr,
    unsigned short* __restrict__ xh2b, float* __restrict__ a_src2, float* __restrict__ a_dst2) {
    // overlay: xs/wsx (phases 1-2) share storage with hs (finish/MFMA phases)
    __shared__ __attribute__((aligned(16))) unsigned char smem[16896];
    uint4* xs = (uint4*)smem;                                   // [256] 4096 B
    uint2* wsx = (uint2*)(smem + 4096);                         // [256] 2048 B
    typedef unsigned short hsrow[264];
    hsrow* hs = (hsrow*)smem;                                   // [32][264] 16896 B
    __shared__ int soffs[33];
    __shared__ float ms[32][33];
    int t = threadIdx.x, lane = t & 63, wid = t >> 6;
    int n0 = blockIdx.x * 32;
    if (t <= 32) soffs[t] = offs[n0 + t];
    float w1r[7][4], b1r[4];
    #pragma unroll
    for (int k = 0; k < 7; ++k)
        #pragma unroll
        for (int h = 0; h < 4; ++h) w1r[k][h] = W1[k * 256 + h * 64 + lane];
    #pragma unroll
    for (int h = 0; h < 4; ++h) b1r[h] = b1[h * 64 + lane];
    __syncthreads();
    int E0 = soffs[0], E1 = soffs[32];
    int g = t >> 3, q = t & 7;
    int go0 = soffs[g], go1 = soffs[g + 1];
    int qh = q >> 1;
    int xsl = (q & 1) ? 0 : 16;    // shift to put selected bf16 in high half
    float mh0 = 0.f, mh1 = 0.f, mh2 = 0.f, mh3 = 0.f;
    for (int C0 = E0; C0 < E1; C0 += 256) {
        int C1 = min(C0 + 256, E1);
        int j = C0 + t;
        if (j < C1) {
            int4 e4 = es2[j];
            xs[t] = xpack[e4.z & SRCMASK];
            wsx[t] = make_uint2((unsigned)e4.x, (unsigned)e4.y);
        }
        __syncthreads();
        int lo = max(go0, C0) - C0, hi = min(go1, C1) - C0;
        for (int jj = lo; jj < hi; ++jj) {
            unsigned xu = ((const unsigned*)&xs[jj])[qh];
            float xv = __uint_as_float((xu << xsl) & 0xFFFF0000u);
            uint2 wv = wsx[jj];
            mh0 = fmaf(bflo(wv.x), xv, mh0);
            mh1 = fmaf(bfhi(wv.x), xv, mh1);
            mh2 = fmaf(bflo(wv.y), xv, mh2);
            mh3 = fmaf(bfhi(wv.y), xv, mh3);
        }
        __syncthreads();
    }
    ms[g][0 * 8 + q] = mh0; ms[g][1 * 8 + q] = mh1;
    ms[g][2 * 8 + q] = mh2; ms[g][3 * 8 + q] = mh3;
    __syncthreads();          // xs/wsx dead from here; hs may now overwrite
    // finish: 8 nodes per wave, lane = channel
    for (int gi = wid * 8; gi < wid * 8 + 8; ++gi) {
        bool has = soffs[gi + 1] > soffs[gi];
        #pragma unroll
        for (int h = 0; h < 4; ++h) {
            float rz = __builtin_amdgcn_rcpf(ms[gi][h * 8 + 7]);
            float a = 0.f;
            #pragma unroll
            for (int k = 0; k < 7; ++k) a = fmaf(ms[gi][h * 8 + k], w1r[k][h], a);
            float mm = (has ? a * rz : 0.f) + b1r[h];
            float hv = mm > 0.f ? mm : (__expf(mm) - 1.f);
            hs[gi][h * 64 + lane] = f2bf(hv);
        }
    }
    __syncthreads();
    // MFMA: 2 node-tiles x 5 col-tiles (ct=4 -> a_src2/a_dst2 columns)
    int row = lane & 15, kg = lane >> 4;
    #pragma unroll
    for (int u = wid; u < 10; u += 4) {
        int nt = u & 1, ct = u >> 1;
        f32x4 acc = {0.f, 0.f, 0.f, 0.f};
        #pragma unroll
        for (int ks = 0; ks < 8; ++ks) {
            bf16x8 av = *(const bf16x8*)&hs[nt * 16 + row][ks * 32 + kg * 8];
            bf16x8 bv = *(const bf16x8*)(W2fr + (((ks * 5 + ct) * 64) + lane) * 8);
            acc = __builtin_amdgcn_mfma_f32_16x16x32_bf16(av, bv, acc, 0, 0, 0);
        }
        if (ct < 4) {
            #pragma unroll
            for (int i = 0; i < 4; ++i)
                xh2b[(n0 + nt * 16 + kg * 4 + i) * 64 + ct * 16 + row] = f2bf(acc[i]);
        } else if (row == 0) {
            #pragma unroll
            for (int i = 0; i < 4; ++i) a_src2[n0 + nt * 16 + kg * 4 + i] = acc[i];
        } else if (row == 1) {
            #pragma unroll
            for (int i = 0; i < 4; ++i) a_dst2[n0 + nt * 16 + kg * 4 + i] = acc[i];
        }
    }
}

// conv2 normalization: single-read, register-carried (2 edges/thread covers span<=512;
// rare overflow handled via LDS z atomics + re-read)
__global__ __launch_bounds__(256) void k_znorm(
    const int4* __restrict__ es2, const int* __restrict__ offs,
    const float* __restrict__ a_src2, const float* __restrict__ a_dst2,
    const int* __restrict__ assign, const float* __restrict__ cb,
    float* __restrict__ cs) {
    __shared__ int soffs[33];
    __shared__ float adL[32];
    __shared__ int asgL[32];
    __shared__ float ewL[512];
    __shared__ float rzL[32];
    __shared__ float zacc[32];
    int t = threadIdx.x;
    int n0 = blockIdx.x * 32;
    if (t <= 32) soffs[t] = offs[n0 + t];
    if (t < 32) { adL[t] = a_dst2[n0 + t]; asgL[t] = assign[n0 + t]; zacc[t] = 0.f; }
    __syncthreads();
    int E0 = soffs[0], E1 = soffs[32];
    float c2 = cb[60];
    // register-carried edges (slots t and 256+t)
    int sx0 = 0, d50 = 0, sx1 = 0, d51 = 0;
    float ew0 = 0.f, ew1 = 0.f;
    bool h0 = (E0 + t) < E1, h1 = (E0 + 256 + t) < E1;
    if (h0) {
        int4 e4 = es2[E0 + t];
        sx0 = e4.z & SRCMASK; d50 = (e4.z >> 25) & 31;
        float lg = a_src2[sx0] + adL[d50] + __int_as_float(e4.w) * c2;
        lg = lg >= 0.f ? lg : 0.2f * lg;
        ew0 = __expf(lg);
        ewL[t] = ew0;
    }
    if (h1) {
        int4 e4 = es2[E0 + 256 + t];
        sx1 = e4.z & SRCMASK; d51 = (e4.z >> 25) & 31;
        float lg = a_src2[sx1] + adL[d51] + __int_as_float(e4.w) * c2;
        lg = lg >= 0.f ? lg : 0.2f * lg;
        ew1 = __expf(lg);
        ewL[256 + t] = ew1;
    }
    // rare overflow edges: accumulate z via LDS atomics
    for (int j = E0 + 512 + t; j < E1; j += 256) {
        int4 e4 = es2[j];
        int d5 = (e4.z >> 25) & 31;
        float lg = a_src2[e4.z & SRCMASK] + adL[d5] + __int_as_float(e4.w) * c2;
        lg = lg >= 0.f ? lg : 0.2f * lg;
        atomicAdd(&zacc[d5], __expf(lg));
    }
    __syncthreads();
    // per-node z from ewL (8 lanes per node)
    int g = t >> 3, q = t & 7;
    int lo = soffs[g] - E0, hi = min(soffs[g + 1] - E0, 512);
    float z = 0.f;
    for (int jj = lo + q; jj < hi; jj += 8) z += ewL[jj];
    z += __shfl_xor(z, 1, 64);
    z += __shfl_xor(z, 2, 64);
    z += __shfl_xor(z, 4, 64);
    if (q == 0) rzL[g] = __builtin_amdgcn_rcpf(z + zacc[g]);
    __syncthreads();
    // pass 2 from registers
    if (h0) atomicAdd(&cs[sx0 * 4 + asgL[d50]], ew0 * rzL[d50]);
    if (h1) atomicAdd(&cs[sx1 * 4 + asgL[d51]], ew1 * rzL[d51]);
    for (int j = E0 + 512 + t; j < E1; j += 256) {
        int4 e4 = es2[j];
        int sx = e4.z & SRCMASK, d5 = (e4.z >> 25) & 31;
        float lg = a_src2[sx] + adL[d5] + __int_as_float(e4.w) * c2;
        lg = lg >= 0.f ? lg : 0.2f * lg;
        atomicAdd(&cs[sx * 4 + asgL[d5]], __expf(lg) * rzL[d5]);
    }
}

// pooling as tiny GEMM: 8 lanes/node, 16B loads, register accumulators, direct gacc atomics
__global__ __launch_bounds__(256) void k_pool(
    const unsigned short* __restrict__ xh2b, const float* __restrict__ cs,
    const int* __restrict__ assign, const float* __restrict__ x,
    float* __restrict__ gacc) {
    __shared__ float csum[264];
    int t = threadIdx.x;
    int q = t & 7, slot = t >> 3;             // 32 node-slots per block
    float a0[8], a1[8], a2[8], a3[8];
    #pragma unroll
    for (int j = 0; j < 8; ++j) { a0[j] = 0.f; a1[j] = 0.f; a2[j] = 0.f; a3[j] = 0.f; }
    float cnt0 = 0.f, cnt1 = 0.f, cnt2 = 0.f, cnt3 = 0.f;
    float cf0 = 0.f, cf1 = 0.f, cf2 = 0.f, cf3 = 0.f;
    for (int n = blockIdx.x * 32 + slot; n < NN; n += NPB * 32) {
        uint4 u = *(const uint4*)(xh2b + n * 64 + q * 8);
        float4 c4 = *(const float4*)(cs + n * 4);
        float xv[8];
        xv[0] = bf2f((unsigned short)u.x); xv[1] = bf2f((unsigned short)(u.x >> 16));
        xv[2] = bf2f((unsigned short)u.y); xv[3] = bf2f((unsigned short)(u.y >> 16));
        xv[4] = bf2f((unsigned short)u.z); xv[5] = bf2f((unsigned short)(u.z >> 16));
        xv[6] = bf2f((unsigned short)u.w); xv[7] = bf2f((unsigned short)(u.w >> 16));
        #pragma unroll
        for (int j = 0; j < 8; ++j) {
            a0[j] = fmaf(c4.x, xv[j], a0[j]);
            a1[j] = fmaf(c4.y, xv[j], a1[j]);
            a2[j] = fmaf(c4.z, xv[j], a2[j]);
            a3[j] = fmaf(c4.w, xv[j], a3[j]);
        }
        if (q == 0) {
            int a = assign[n];
            float xf = x[n * 7 + 6];
            cnt0 += (a == 0) ? 1.f : 0.f;  cf0 += (a == 0) ? xf : 0.f;
            cnt1 += (a == 1) ? 1.f : 0.f;  cf1 += (a == 1) ? xf : 0.f;
            cnt2 += (a == 2) ? 1.f : 0.f;  cf2 += (a == 2) ? xf : 0.f;
            cnt3 += (a == 3) ? 1.f : 0.f;  cf3 += (a == 3) ? xf : 0.f;
        }
    }
    for (int i = t; i < 264; i += 256) csum[i] = 0.f;
    __syncthreads();
    int base = q * 8;
    #pragma unroll
    for (int j = 0; j < 8; ++j) {
        atomicAdd(&csum[0 * 64 + base + j], a0[j]);
        atomicAdd(&csum[1 * 64 + base + j], a1[j]);
        atomicAdd(&csum[2 * 64 + base + j], a2[j]);
        atomicAdd(&csum[3 * 64 + base + j], a3[j]);
    }
    if (q == 0) {
        atomicAdd(&csum[256], cnt0); atomicAdd(&csum[257], cnt1);
        atomicAdd(&csum[258], cnt2); atomicAdd(&csum[259], cnt3);
        atomicAdd(&csum[260], cf0);  atomicAdd(&csum[261], cf1);
        atomicAdd(&csum[262], cf2);  atomicAdd(&csum[263], cf3);
    }
    __syncthreads();
    for (int i = t; i < 264; i += 256) atomicAdd(&gacc[i], csum[i]);
}

// final head (256 threads): cluster means (+cnt*b2), actor MLP + softmax, critic MLP
__global__ __launch_bounds__(256) void k_head(
    const float* __restrict__ gacc, const float* __restrict__ b2,
    const float* __restrict__ A1, const float* __restrict__ ba1,
    const float* __restrict__ A2, const float* __restrict__ ba2,
    const float* __restrict__ C1, const float* __restrict__ bc1,
    const float* __restrict__ C2, const float* __restrict__ bc2,
    float* __restrict__ out) {
    __shared__ float zc[4][64];
    __shared__ float cfs[4];
    __shared__ float logits[4];
    __shared__ float vpart[4][64];
    int t = threadIdx.x;
    int j = t & 63, wv = t >> 6;   // wave wv handles cluster wv
    float cnt = gacc[256 + wv];
    float den = fmaxf(cnt, 1.f);
    zc[wv][j] = (cnt > 0.f) ? (gacc[wv * 64 + j] + cnt * b2[j]) / den : 0.f;
    if (t < 4) {
        float cc = gacc[256 + t];
        cfs[t] = (cc > 0.f) ? gacc[260 + t] / fmaxf(cc, 1.f) : 0.f;
    }
    __syncthreads();
    // actor: cluster wv
    float tv = ba1[j];
    for (int k = 0; k < 64; ++k) tv = fmaf(zc[wv][k], A1[k * 64 + j], tv);
    tv = fmaf(cfs[wv], A1[64 * 64 + j], tv);
    tv = fmaxf(tv, 0.f);
    float sred = wave_reduce_sum(tv * A2[j]);
    if (j == 0) logits[wv] = sred + ba2[0];
    // critic partials: wave wv covers k in [wv*64, (wv+1)*64)
    float vj = (wv == 0) ? bc1[j] : 0.f;
    for (int kk = 0; kk < 64; ++kk) vj = fmaf(zc[wv][kk], C1[(wv * 64 + kk) * 64 + j], vj);
    vpart[wv][j] = vj;
    __syncthreads();
    if (wv == 0) {
        float vv = fmaxf(vpart[0][j] + vpart[1][j] + vpart[2][j] + vpart[3][j], 0.f);
        float v = wave_reduce_sum(vv * C2[j]);
        if (j == 0) {
            float m = fmaxf(fmaxf(logits[0], logits[1]), fmaxf(logits[2], logits[3]));
            float e0 = __expf(logits[0] - m), e1 = __expf(logits[1] - m);
            float e2 = __expf(logits[2] - m), e3 = __expf(logits[3] - m);
            float sum = e0 + e1 + e2 + e3;
            out[0] = e0 / sum; out[1] = e1 / sum; out[2] = e2 / sum; out[3] = e3 / sum;
            out[4] = v + bc2[0];
        }
    }
    out[5 + wv * 64 + j] = zc[wv][j];
}

extern "C" void kernel_launch(void* const* d_in, const int* in_sizes, int n_in,
                              void* d_out, int out_size, void* d_ws, size_t ws_size,
                              hipStream_t stream) {
    const float* x    = (const float*)d_in[0];
    const int*   ei   = (const int*)d_in[1];
    const float* ea   = (const float*)d_in[2];
    const int*   asg  = (const int*)d_in[3];
    const float* W1   = (const float*)d_in[4];
    const float* as1  = (const float*)d_in[5];
    const float* ad1  = (const float*)d_in[6];
    const float* We1  = (const float*)d_in[7];
    const float* ae1  = (const float*)d_in[8];
    const float* b1   = (const float*)d_in[9];
    const float* W2   = (const float*)d_in[10];
    const float* as2  = (const float*)d_in[11];
    const float* ad2  = (const float*)d_in[12];
    const float* We2  = (const float*)d_in[13];
    const float* ae2  = (const float*)d_in[14];
    const float* b2   = (const float*)d_in[15];
    const float* A1   = (const float*)d_in[16];
    const float* ba1  = (const float*)d_in[17];
    const float* A2   = (const float*)d_in[18];
    const float* ba2  = (const float*)d_in[19];
    const float* C1   = (const float*)d_in[20];
    const float* bc1  = (const float*)d_in[21];
    const float* C2   = (const float*)d_in[22];
    const float* bc2  = (const float*)d_in[23];
    const int* src = ei;
    const int* dst = ei + NE;

    char* w = (char*)d_ws;
    size_t off = 0;
    auto alloc = [&](size_t bytes) -> void* {
        void* p = w + off;
        off += (bytes + 255) & ~(size_t)255;
        return p;
    };
    // contiguous zero-init region: hist | cs | gacc
    int*   hist   = (int*)alloc(NN * sizeof(int));
    float* cs     = (float*)alloc(NN * 4 * sizeof(float));
    float* gacc   = (float*)alloc(264 * sizeof(float));
    size_t zspan  = (size_t)((char*)gacc + 264 * sizeof(float) - (char*)hist);
    uint4* anode  = (uint4*)alloc(NN * sizeof(uint4));
    float* a_src2 = (float*)alloc(NN * sizeof(float));
    float* a_dst2 = (float*)alloc(NN * sizeof(float));
    uint4* xpack  = (uint4*)alloc(NN * sizeof(uint4));
    int*   offs   = (int*)alloc((NN + 1) * sizeof(int));
    int*   rank   = (int*)alloc(NE * sizeof(int));
    int*   bsum   = (int*)alloc(128 * sizeof(int));
    int*   bexcl  = (int*)alloc(128 * sizeof(int));
    int4*  es2    = (int4*)alloc(NE * sizeof(int4));
    unsigned short* xh2b = (unsigned short*)alloc(NN * 64 * sizeof(unsigned short));
    unsigned short* W2fr = (unsigned short*)alloc(20480 * sizeof(unsigned short));
    float* cb     = (float*)alloc(64 * sizeof(float));
    (void)ws_size; (void)n_in; (void)in_sizes; (void)out_size;

    (void)hipMemsetAsync(hist, 0, zspan, stream);

    k_pre<<<81, 256, 0, stream>>>(W1, as1, ad1, We1, ae1, We2, ae2, W2, as2, ad2, cb, W2fr);
    k_node1h<<<(NN + 255) / 256, 256, 0, stream>>>(x, cb, dst, anode, xpack, hist, rank);
    k_scanA<<<98, 1024, 0, stream>>>(hist, bsum);
    k_scanB<<<1, 128, 0, stream>>>(bsum, bexcl);
    k_scanC<<<98, 1024, 0, stream>>>(hist, bexcl, offs);
    k_scatter<<<(NE / 2 + 255) / 256, 256, 0, stream>>>(src, dst, ea, rank, offs,
                                                        anode, cb, es2);
    k_conv1red<<<NN / 32, 256, 0, stream>>>(xpack, W1, b1, offs, es2,
                                            W2fr, xh2b, a_src2, a_dst2);
    k_znorm<<<NN / 32, 256, 0, stream>>>(es2, offs, a_src2, a_dst2, asg, cb, cs);
    k_pool<<<NPB, 256, 0, stream>>>(xh2b, cs, asg, x, gacc);
    k_head<<<1, 256, 0, stream>>>(gacc, b2, A1, ba1, A2, ba2, C1, bc1, C2, bc2, (float*)d_out);
}

// Round 16
// 186.988 us; speedup vs baseline: 1.1592x; 1.0284x over previous
//
#include <hip/hip_runtime.h>

#define NN 100000
#define NE 800000
#define NZB (NN / 32)          // 3125 zpool blocks
#define SRCMASK 0x01FFFFFF

typedef short bf16x8 __attribute__((ext_vector_type(8)));
typedef float f32x4 __attribute__((ext_vector_type(4)));

__device__ __forceinline__ float wave_reduce_sum(float v) {
    #pragma unroll
    for (int o = 32; o > 0; o >>= 1) v += __shfl_down(v, o, 64);
    return v; // valid in lane 0
}

__device__ __forceinline__ unsigned short f2bf(float f) {
    unsigned u = __float_as_uint(f);
    unsigned r = (u + 0x7FFFu + ((u >> 16) & 1u)) >> 16;
    return (unsigned short)r;
}
__device__ __forceinline__ float bf2f(unsigned short b) {
    return __uint_as_float(((unsigned)b) << 16);
}
__device__ __forceinline__ float bflo(unsigned u) {   // low bf16 of u32
    return __uint_as_float(u << 16);
}
__device__ __forceinline__ float bfhi(unsigned u) {   // high bf16 of u32
    return __uint_as_float(u & 0xFFFF0000u);
}
__device__ __forceinline__ unsigned pk2(float a, float b) {
    return (unsigned)f2bf(a) | ((unsigned)f2bf(b) << 16);
}

// cb layout (floats): [0..27] vs1(k*4+h)  [28..55] vd1  [56..59] c1[h]  [60] c2
// W2fr: 5 col-tiles x 8 k-slices, B-fragment order; tile ct=4 col0=W2@as2, col1=W2@ad2
__global__ void k_pre(const float* __restrict__ W1, const float* __restrict__ as1,
                      const float* __restrict__ ad1,
                      const float* __restrict__ We1, const float* __restrict__ ae1,
                      const float* __restrict__ We2, const float* __restrict__ ae2,
                      const float* __restrict__ W2, const float* __restrict__ as2,
                      const float* __restrict__ ad2,
                      float* __restrict__ cb, unsigned short* __restrict__ W2fr) {
    int t = threadIdx.x;
    if (blockIdx.x == 0) {
        if (t < 28) {
            int k = t >> 2, h = t & 3;
            float s = 0.f, d = 0.f;
            for (int c = 0; c < 64; ++c) {
                float w = W1[k * 256 + h * 64 + c];
                s += w * as1[h * 64 + c];
                d += w * ad1[h * 64 + c];
            }
            cb[t] = s; cb[28 + t] = d;
        } else if (t < 32) {
            int h = t - 28;
            float s = 0.f;
            for (int c = 0; c < 64; ++c) s += We1[h * 64 + c] * ae1[h * 64 + c];
            cb[56 + h] = s;
        } else if (t == 32) {
            float s = 0.f;
            for (int c = 0; c < 64; ++c) s += We2[c] * ae2[c];
            cb[60] = s;
        }
    } else {
        int o = (blockIdx.x - 1) * 256 + t;        // 0..20479
        if (o >= 20480) return;
        int i = o & 7, l = (o >> 3) & 63, rest = o >> 9;
        int ct = rest % 5, ks = rest / 5;
        int k = ks * 32 + ((l >> 4) * 8) + i;
        int cl = l & 15;
        if (ct < 4) {
            W2fr[o] = f2bf(W2[k * 64 + ct * 16 + cl]);
        } else if (cl < 2) {
            const float* av = (cl == 0) ? as2 : ad2;
            float s = 0.f;
            for (int j = 0; j < 64; ++j) s += W2[k * 64 + j] * av[j];
            W2fr[o] = f2bf(s);
        } else {
            W2fr[o] = 0;
        }
    }
}

// per-node: packed bf16 attention record + packed bf16 x-record;
// fused dst histogram capturing per-edge rank (coalesced int4 stores)
__global__ void k_node1h(const float* __restrict__ x, const float* __restrict__ cb,
                         const int* __restrict__ dst,
                         uint4* __restrict__ anode, uint4* __restrict__ xpack,
                         int* __restrict__ hist, int* __restrict__ rank) {
    int n = blockIdx.x * 256 + threadIdx.x;
    if (n >= NN) return;
    float xv[7];
    #pragma unroll
    for (int k = 0; k < 7; ++k) xv[k] = x[n * 7 + k];
    float s[4] = {0.f, 0.f, 0.f, 0.f}, d[4] = {0.f, 0.f, 0.f, 0.f};
    #pragma unroll
    for (int k = 0; k < 7; ++k)
        #pragma unroll
        for (int h = 0; h < 4; ++h) {
            s[h] += xv[k] * cb[k * 4 + h];
            d[h] += xv[k] * cb[28 + k * 4 + h];
        }
    anode[n] = make_uint4(pk2(s[0], s[1]), pk2(s[2], s[3]), pk2(d[0], d[1]), pk2(d[2], d[3]));
    xpack[n] = make_uint4(pk2(xv[0], xv[1]), pk2(xv[2], xv[3]),
                          pk2(xv[4], xv[5]), pk2(xv[6], 1.f));
    // histogram + rank: edges [n*8, n*8+8)
    int e0 = n * 8;
    int4 d0 = *(const int4*)(dst + e0);
    int4 d1 = *(const int4*)(dst + e0 + 4);
    int4 r0, r1;
    r0.x = atomicAdd(&hist[d0.x], 1); r0.y = atomicAdd(&hist[d0.y], 1);
    r0.z = atomicAdd(&hist[d0.z], 1); r0.w = atomicAdd(&hist[d0.w], 1);
    r1.x = atomicAdd(&hist[d1.x], 1); r1.y = atomicAdd(&hist[d1.y], 1);
    r1.z = atomicAdd(&hist[d1.z], 1); r1.w = atomicAdd(&hist[d1.w], 1);
    *(int4*)(rank + e0) = r0;
    *(int4*)(rank + e0 + 4) = r1;
}

// --- 3-phase parallel exclusive scan over hist[NN] -> offs[NN+1] ---
__global__ __launch_bounds__(1024) void k_scanA(const int* __restrict__ hist,
                                                int* __restrict__ bsum) {
    __shared__ int ws[16];
    int i = blockIdx.x * 1024 + threadIdx.x;
    int lane = threadIdx.x & 63, wid = threadIdx.x >> 6;
    int v = (i < NN) ? hist[i] : 0;
    #pragma unroll
    for (int o = 32; o; o >>= 1) v += __shfl_down(v, o, 64);
    if (lane == 0) ws[wid] = v;
    __syncthreads();
    if (wid == 0) {
        int u = (lane < 16) ? ws[lane] : 0;
        #pragma unroll
        for (int o = 8; o; o >>= 1) u += __shfl_down(u, o, 64);
        if (lane == 0) bsum[blockIdx.x] = u;
    }
}

__global__ void k_scanB(const int* __restrict__ bsum, int* __restrict__ bexcl) {
    __shared__ int w0tot;
    int t = threadIdx.x, lane = t & 63, wid = t >> 6;
    int v = (t < 98) ? bsum[t] : 0;
    int s = v;
    #pragma unroll
    for (int d = 1; d < 64; d <<= 1) { int u = __shfl_up(s, d, 64); if (lane >= d) s += u; }
    if (t == 63) w0tot = s;
    __syncthreads();
    if (wid == 1) s += w0tot;
    if (t < 98) bexcl[t] = s - v;
}

__global__ __launch_bounds__(1024) void k_scanC(const int* __restrict__ hist,
                                                const int* __restrict__ bexcl,
                                                int* __restrict__ offs) {
    __shared__ int ws[16];
    int b = blockIdx.x;
    int i = b * 1024 + threadIdx.x;
    int lane = threadIdx.x & 63, wid = threadIdx.x >> 6;
    int v = (i < NN) ? hist[i] : 0;
    int s = v;
    #pragma unroll
    for (int d = 1; d < 64; d <<= 1) { int u = __shfl_up(s, d, 64); if (lane >= d) s += u; }
    if (lane == 63) ws[wid] = s;
    __syncthreads();
    if (wid == 0) {
        int u2 = (lane < 16) ? ws[lane] : 0;
        #pragma unroll
        for (int d = 1; d < 16; d <<= 1) { int uu = __shfl_up(u2, d, 64); if (lane >= d) u2 += uu; }
        if (lane < 16) ws[lane] = u2;
    }
    __syncthreads();
    int incl = s + (wid ? ws[wid - 1] : 0) + bexcl[b];
    if (i < NN) offs[i + 1] = incl;
    if (i == 0) offs[0] = 0;
}

// scatter + conv1 edge weights; atomic-free (pos = offs[dst] + rank); 2 edges/thread
__global__ void k_scatter(const int* __restrict__ src, const int* __restrict__ dst,
                          const float* __restrict__ ea, const int* __restrict__ rank,
                          const int* __restrict__ offs,
                          const uint4* __restrict__ anode, const float* __restrict__ cb,
                          int4* __restrict__ es2) {
    int e0 = (blockIdx.x * 256 + threadIdx.x) * 2;
    if (e0 >= NE) return;
    int2 s2 = *(const int2*)(src + e0);
    int2 d2 = *(const int2*)(dst + e0);
    float2 a2 = *(const float2*)(ea + e0);
    int2 r2 = *(const int2*)(rank + e0);
    float c56 = cb[56], c57 = cb[57], c58 = cb[58], c59 = cb[59];
    #pragma unroll
    for (int u = 0; u < 2; ++u) {
        int s = u ? s2.y : s2.x;
        int d = u ? d2.y : d2.x;
        float eav = u ? a2.y : a2.x;
        int pos = offs[d] + (u ? r2.y : r2.x);
        uint4 ar = anode[s];
        uint4 br = anode[d];
        float lg0 = bflo(ar.x) + bflo(br.z) + eav * c56;
        float lg1 = bfhi(ar.x) + bfhi(br.z) + eav * c57;
        float lg2 = bflo(ar.y) + bflo(br.w) + eav * c58;
        float lg3 = bfhi(ar.y) + bfhi(br.w) + eav * c59;
        lg0 = lg0 >= 0.f ? lg0 : 0.2f * lg0;
        lg1 = lg1 >= 0.f ? lg1 : 0.2f * lg1;
        lg2 = lg2 >= 0.f ? lg2 : 0.2f * lg2;
        lg3 = lg3 >= 0.f ? lg3 : 0.2f * lg3;
        unsigned w01 = pk2(__expf(lg0), __expf(lg1));
        unsigned w23 = pk2(__expf(lg2), __expf(lg3));
        es2[pos] = make_int4((int)w01, (int)w23, s | ((d & 31) << 25), __float_as_int(eav));
    }
}

// fused conv1: packed-LDS two-phase segmented reduce -> h -> MFMA
// 5th col-tile computes a_src2/a_dst2 directly (no shfl epilogue)
__global__ __launch_bounds__(256, 7) void k_conv1red(
    const uint4* __restrict__ xpack, const float* __restrict__ W1, const float* __restrict__ b1,
    const int* __restrict__ offs, const int4* __restrict__ es2,
    const unsigned short* __restrict__ W2fr,
    unsigned short* __restrict__ xh2b, float* __restrict__ a_src2, float* __restrict__ a_dst2) {
    // overlay: xs/wsx (phases 1-2) share storage with hs (finish/MFMA phases)
    __shared__ __attribute__((aligned(16))) unsigned char smem[16896];
    uint4* xs = (uint4*)smem;                                   // [256] 4096 B
    uint2* wsx = (uint2*)(smem + 4096);                         // [256] 2048 B
    typedef unsigned short hsrow[264];
    hsrow* hs = (hsrow*)smem;                                   // [32][264] 16896 B
    __shared__ int soffs[33];
    __shared__ float ms[32][33];
    int t = threadIdx.x, lane = t & 63, wid = t >> 6;
    int n0 = blockIdx.x * 32;
    if (t <= 32) soffs[t] = offs[n0 + t];
    float w1r[7][4], b1r[4];
    #pragma unroll
    for (int k = 0; k < 7; ++k)
        #pragma unroll
        for (int h = 0; h < 4; ++h) w1r[k][h] = W1[k * 256 + h * 64 + lane];
    #pragma unroll
    for (int h = 0; h < 4; ++h) b1r[h] = b1[h * 64 + lane];
    __syncthreads();
    int E0 = soffs[0], E1 = soffs[32];
    int g = t >> 3, q = t & 7;
    int go0 = soffs[g], go1 = soffs[g + 1];
    int qh = q >> 1;
    int xsl = (q & 1) ? 0 : 16;    // shift to put selected bf16 in high half
    float mh0 = 0.f, mh1 = 0.f, mh2 = 0.f, mh3 = 0.f;
    for (int C0 = E0; C0 < E1; C0 += 256) {
        int C1 = min(C0 + 256, E1);
        int j = C0 + t;
        if (j < C1) {
            int4 e4 = es2[j];
            xs[t] = xpack[e4.z & SRCMASK];
            wsx[t] = make_uint2((unsigned)e4.x, (unsigned)e4.y);
        }
        __syncthreads();
        int lo = max(go0, C0) - C0, hi = min(go1, C1) - C0;
        for (int jj = lo; jj < hi; ++jj) {
            unsigned xu = ((const unsigned*)&xs[jj])[qh];
            float xv = __uint_as_float((xu << xsl) & 0xFFFF0000u);
            uint2 wv = wsx[jj];
            mh0 = fmaf(bflo(wv.x), xv, mh0);
            mh1 = fmaf(bfhi(wv.x), xv, mh1);
            mh2 = fmaf(bflo(wv.y), xv, mh2);
            mh3 = fmaf(bfhi(wv.y), xv, mh3);
        }
        __syncthreads();
    }
    ms[g][0 * 8 + q] = mh0; ms[g][1 * 8 + q] = mh1;
    ms[g][2 * 8 + q] = mh2; ms[g][3 * 8 + q] = mh3;
    __syncthreads();          // xs/wsx dead from here; hs may now overwrite
    // finish: 8 nodes per wave, lane = channel
    for (int gi = wid * 8; gi < wid * 8 + 8; ++gi) {
        bool has = soffs[gi + 1] > soffs[gi];
        #pragma unroll
        for (int h = 0; h < 4; ++h) {
            float rz = __builtin_amdgcn_rcpf(ms[gi][h * 8 + 7]);
            float a = 0.f;
            #pragma unroll
            for (int k = 0; k < 7; ++k) a = fmaf(ms[gi][h * 8 + k], w1r[k][h], a);
            float mm = (has ? a * rz : 0.f) + b1r[h];
            float hv = mm > 0.f ? mm : (__expf(mm) - 1.f);
            hs[gi][h * 64 + lane] = f2bf(hv);
        }
    }
    __syncthreads();
    // MFMA: 2 node-tiles x 5 col-tiles (ct=4 -> a_src2/a_dst2 columns)
    int row = lane & 15, kg = lane >> 4;
    #pragma unroll
    for (int u = wid; u < 10; u += 4) {
        int nt = u & 1, ct = u >> 1;
        f32x4 acc = {0.f, 0.f, 0.f, 0.f};
        #pragma unroll
        for (int ks = 0; ks < 8; ++ks) {
            bf16x8 av = *(const bf16x8*)&hs[nt * 16 + row][ks * 32 + kg * 8];
            bf16x8 bv = *(const bf16x8*)(W2fr + (((ks * 5 + ct) * 64) + lane) * 8);
            acc = __builtin_amdgcn_mfma_f32_16x16x32_bf16(av, bv, acc, 0, 0, 0);
        }
        if (ct < 4) {
            #pragma unroll
            for (int i = 0; i < 4; ++i)
                xh2b[(n0 + nt * 16 + kg * 4 + i) * 64 + ct * 16 + row] = f2bf(acc[i]);
        } else if (row == 0) {
            #pragma unroll
            for (int i = 0; i < 4; ++i) a_src2[n0 + nt * 16 + kg * 4 + i] = acc[i];
        } else if (row == 1) {
            #pragma unroll
            for (int i = 0; i < 4; ++i) a_dst2[n0 + nt * 16 + kg * 4 + i] = acc[i];
        }
    }
}

// conv2 normalization + fused cluster pooling (no global atomics):
// pass 1: ew/src -> LDS (span<=512 register-free; overflow via LDS z atomics)
// pass 2: per-lane gather xh2b[src] 16B chunk, accumulate w*row into regs,
//         reduce into LDS csum once per node; write coalesced block partials.
__global__ __launch_bounds__(256) void k_zpool(
    const int4* __restrict__ es2, const int* __restrict__ offs,
    const float* __restrict__ a_src2, const float* __restrict__ a_dst2,
    const int* __restrict__ assign, const float* __restrict__ cb,
    const unsigned short* __restrict__ xh2b, const float* __restrict__ x,
    float* __restrict__ partial) {
    __shared__ int soffs[33];
    __shared__ float adL[32];
    __shared__ int asgL[32];
    __shared__ float ewL[512];
    __shared__ int sL[512];
    __shared__ float rzL[32];
    __shared__ float zacc[32];
    __shared__ float csum[264];
    int t = threadIdx.x;
    int n0 = blockIdx.x * 32;
    if (t <= 32) soffs[t] = offs[n0 + t];
    if (t < 32) { adL[t] = a_dst2[n0 + t]; asgL[t] = assign[n0 + t]; zacc[t] = 0.f; }
    for (int i = t; i < 264; i += 256) csum[i] = 0.f;
    __syncthreads();
    int E0 = soffs[0], E1 = soffs[32];
    float c2 = cb[60];
    if (E0 + t < E1) {
        int4 e4 = es2[E0 + t];
        int sx = e4.z & SRCMASK;
        int d5 = (e4.z >> 25) & 31;
        float lg = a_src2[sx] + adL[d5] + __int_as_float(e4.w) * c2;
        lg = lg >= 0.f ? lg : 0.2f * lg;
        ewL[t] = __expf(lg);
        sL[t] = sx;
    }
    if (E0 + 256 + t < E1) {
        int4 e4 = es2[E0 + 256 + t];
        int sx = e4.z & SRCMASK;
        int d5 = (e4.z >> 25) & 31;
        float lg = a_src2[sx] + adL[d5] + __int_as_float(e4.w) * c2;
        lg = lg >= 0.f ? lg : 0.2f * lg;
        ewL[256 + t] = __expf(lg);
        sL[256 + t] = sx;
    }
    // rare overflow edges: accumulate z via LDS atomics
    for (int j = E0 + 512 + t; j < E1; j += 256) {
        int4 e4 = es2[j];
        int d5 = (e4.z >> 25) & 31;
        float lg = a_src2[e4.z & SRCMASK] + adL[d5] + __int_as_float(e4.w) * c2;
        lg = lg >= 0.f ? lg : 0.2f * lg;
        atomicAdd(&zacc[d5], __expf(lg));
    }
    __syncthreads();
    // per-node z from ewL (8 lanes per node)
    int g = t >> 3, q = t & 7;
    int lo = soffs[g] - E0, hi = soffs[g + 1] - E0;
    int hicap = min(hi, 512);
    float z = 0.f;
    for (int jj = lo + q; jj < hicap; jj += 8) z += ewL[jj];
    z += __shfl_xor(z, 1, 64);
    z += __shfl_xor(z, 2, 64);
    z += __shfl_xor(z, 4, 64);
    if (q == 0) rzL[g] = __builtin_amdgcn_rcpf(z + zacc[g]);
    __syncthreads();
    // pass 2: gather xh2b rows, accumulate weighted into regs
    float rzv = rzL[g];
    float a0 = 0.f, a1 = 0.f, a2 = 0.f, a3 = 0.f;
    float a4 = 0.f, a5 = 0.f, a6 = 0.f, a7 = 0.f;
    for (int jj = lo; jj < hicap; ++jj) {
        float wv = ewL[jj] * rzv;
        int sj = sL[jj];
        uint4 u = *(const uint4*)(xh2b + sj * 64 + q * 8);
        a0 = fmaf(wv, bflo(u.x), a0); a1 = fmaf(wv, bfhi(u.x), a1);
        a2 = fmaf(wv, bflo(u.y), a2); a3 = fmaf(wv, bfhi(u.y), a3);
        a4 = fmaf(wv, bflo(u.z), a4); a5 = fmaf(wv, bfhi(u.z), a5);
        a6 = fmaf(wv, bflo(u.w), a6); a7 = fmaf(wv, bfhi(u.w), a7);
    }
    // rare overflow edges (recompute ew)
    for (int jo = max(lo, 512); jo < hi; ++jo) {
        int4 e4 = es2[E0 + jo];
        int sx = e4.z & SRCMASK;
        float lg = a_src2[sx] + adL[g] + __int_as_float(e4.w) * c2;
        lg = lg >= 0.f ? lg : 0.2f * lg;
        float wv = __expf(lg) * rzv;
        uint4 u = *(const uint4*)(xh2b + sx * 64 + q * 8);
        a0 = fmaf(wv, bflo(u.x), a0); a1 = fmaf(wv, bfhi(u.x), a1);
        a2 = fmaf(wv, bflo(u.y), a2); a3 = fmaf(wv, bfhi(u.y), a3);
        a4 = fmaf(wv, bflo(u.z), a4); a5 = fmaf(wv, bfhi(u.z), a5);
        a6 = fmaf(wv, bflo(u.w), a6); a7 = fmaf(wv, bfhi(u.w), a7);
    }
    int cb_ = asgL[g] * 64 + q * 8;
    atomicAdd(&csum[cb_ + 0], a0); atomicAdd(&csum[cb_ + 1], a1);
    atomicAdd(&csum[cb_ + 2], a2); atomicAdd(&csum[cb_ + 3], a3);
    atomicAdd(&csum[cb_ + 4], a4); atomicAdd(&csum[cb_ + 5], a5);
    atomicAdd(&csum[cb_ + 6], a6); atomicAdd(&csum[cb_ + 7], a7);
    if (t < 32) {
        int c = asgL[t];
        atomicAdd(&csum[256 + c], 1.f);
        atomicAdd(&csum[260 + c], x[(n0 + t) * 7 + 6]);
    }
    __syncthreads();
    for (int i = t; i < 264; i += 256) partial[blockIdx.x * 264 + i] = csum[i];
}

// reduce partials -> gacc[264]
__global__ void k_red(const float* __restrict__ partial, float* __restrict__ gacc) {
    int i = blockIdx.x;   // 264 blocks x 64 threads
    float s = 0.f;
    for (int b = threadIdx.x; b < NZB; b += 64) s += partial[b * 264 + i];
    s = wave_reduce_sum(s);
    if (threadIdx.x == 0) gacc[i] = s;
}

// final head (256 threads): cluster means (+cnt*b2), actor MLP + softmax, critic MLP
__global__ __launch_bounds__(256) void k_head(
    const float* __restrict__ gacc, const float* __restrict__ b2,
    const float* __restrict__ A1, const float* __restrict__ ba1,
    const float* __restrict__ A2, const float* __restrict__ ba2,
    const float* __restrict__ C1, const float* __restrict__ bc1,
    const float* __restrict__ C2, const float* __restrict__ bc2,
    float* __restrict__ out) {
    __shared__ float zc[4][64];
    __shared__ float cfs[4];
    __shared__ float logits[4];
    __shared__ float vpart[4][64];
    int t = threadIdx.x;
    int j = t & 63, wv = t >> 6;   // wave wv handles cluster wv
    float cnt = gacc[256 + wv];
    float den = fmaxf(cnt, 1.f);
    zc[wv][j] = (cnt > 0.f) ? (gacc[wv * 64 + j] + cnt * b2[j]) / den : 0.f;
    if (t < 4) {
        float cc = gacc[256 + t];
        cfs[t] = (cc > 0.f) ? gacc[260 + t] / fmaxf(cc, 1.f) : 0.f;
    }
    __syncthreads();
    // actor: cluster wv
    float tv = ba1[j];
    for (int k = 0; k < 64; ++k) tv = fmaf(zc[wv][k], A1[k * 64 + j], tv);
    tv = fmaf(cfs[wv], A1[64 * 64 + j], tv);
    tv = fmaxf(tv, 0.f);
    float sred = wave_reduce_sum(tv * A2[j]);
    if (j == 0) logits[wv] = sred + ba2[0];
    // critic partials: wave wv covers k in [wv*64, (wv+1)*64)
    float vj = (wv == 0) ? bc1[j] : 0.f;
    for (int kk = 0; kk < 64; ++kk) vj = fmaf(zc[wv][kk], C1[(wv * 64 + kk) * 64 + j], vj);
    vpart[wv][j] = vj;
    __syncthreads();
    if (wv == 0) {
        float vv = fmaxf(vpart[0][j] + vpart[1][j] + vpart[2][j] + vpart[3][j], 0.f);
        float v = wave_reduce_sum(vv * C2[j]);
        if (j == 0) {
            float m = fmaxf(fmaxf(logits[0], logits[1]), fmaxf(logits[2], logits[3]));
            float e0 = __expf(logits[0] - m), e1 = __expf(logits[1] - m);
            float e2 = __expf(logits[2] - m), e3 = __expf(logits[3] - m);
            float sum = e0 + e1 + e2 + e3;
            out[0] = e0 / sum; out[1] = e1 / sum; out[2] = e2 / sum; out[3] = e3 / sum;
            out[4] = v + bc2[0];
        }
    }
    out[5 + wv * 64 + j] = zc[wv][j];
}

extern "C" void kernel_launch(void* const* d_in, const int* in_sizes, int n_in,
                              void* d_out, int out_size, void* d_ws, size_t ws_size,
                              hipStream_t stream) {
    const float* x    = (const float*)d_in[0];
    const int*   ei   = (const int*)d_in[1];
    const float* ea   = (const float*)d_in[2];
    const int*   asg  = (const int*)d_in[3];
    const float* W1   = (const float*)d_in[4];
    const float* as1  = (const float*)d_in[5];
    const float* ad1  = (const float*)d_in[6];
    const float* We1  = (const float*)d_in[7];
    const float* ae1  = (const float*)d_in[8];
    const float* b1   = (const float*)d_in[9];
    const float* W2   = (const float*)d_in[10];
    const float* as2  = (const float*)d_in[11];
    const float* ad2  = (const float*)d_in[12];
    const float* We2  = (const float*)d_in[13];
    const float* ae2  = (const float*)d_in[14];
    const float* b2   = (const float*)d_in[15];
    const float* A1   = (const float*)d_in[16];
    const float* ba1  = (const float*)d_in[17];
    const float* A2   = (const float*)d_in[18];
    const float* ba2  = (const float*)d_in[19];
    const float* C1   = (const float*)d_in[20];
    const float* bc1  = (const float*)d_in[21];
    const float* C2   = (const float*)d_in[22];
    const float* bc2  = (const float*)d_in[23];
    const int* src = ei;
    const int* dst = ei + NE;

    char* w = (char*)d_ws;
    size_t off = 0;
    auto alloc = [&](size_t bytes) -> void* {
        void* p = w + off;
        off += (bytes + 255) & ~(size_t)255;
        return p;
    };
    int*   hist   = (int*)alloc(NN * sizeof(int));
    float* gacc   = (float*)alloc(264 * sizeof(float));
    float* partial= (float*)alloc((size_t)NZB * 264 * sizeof(float));
    uint4* anode  = (uint4*)alloc(NN * sizeof(uint4));
    float* a_src2 = (float*)alloc(NN * sizeof(float));
    float* a_dst2 = (float*)alloc(NN * sizeof(float));
    uint4* xpack  = (uint4*)alloc(NN * sizeof(uint4));
    int*   offs   = (int*)alloc((NN + 1) * sizeof(int));
    int*   rank   = (int*)alloc(NE * sizeof(int));
    int*   bsum   = (int*)alloc(128 * sizeof(int));
    int*   bexcl  = (int*)alloc(128 * sizeof(int));
    int4*  es2    = (int4*)alloc(NE * sizeof(int4));
    unsigned short* xh2b = (unsigned short*)alloc(NN * 64 * sizeof(unsigned short));
    unsigned short* W2fr = (unsigned short*)alloc(20480 * sizeof(unsigned short));
    float* cb     = (float*)alloc(64 * sizeof(float));
    (void)ws_size; (void)n_in; (void)in_sizes; (void)out_size;

    (void)hipMemsetAsync(hist, 0, NN * sizeof(int), stream);

    k_pre<<<81, 256, 0, stream>>>(W1, as1, ad1, We1, ae1, We2, ae2, W2, as2, ad2, cb, W2fr);
    k_node1h<<<(NN + 255) / 256, 256, 0, stream>>>(x, cb, dst, anode, xpack, hist, rank);
    k_scanA<<<98, 1024, 0, stream>>>(hist, bsum);
    k_scanB<<<1, 128, 0, stream>>>(bsum, bexcl);
    k_scanC<<<98, 1024, 0, stream>>>(hist, bexcl, offs);
    k_scatter<<<(NE / 2 + 255) / 256, 256, 0, stream>>>(src, dst, ea, rank, offs,
                                                        anode, cb, es2);
    k_conv1red<<<NN / 32, 256, 0, stream>>>(xpack, W1, b1, offs, es2,
                                            W2fr, xh2b, a_src2, a_dst2);
    k_zpool<<<NZB, 256, 0, stream>>>(es2, offs, a_src2, a_dst2, asg, cb, xh2b, x, partial);
    k_red<<<264, 64, 0, stream>>>(partial, gacc);
    k_head<<<1, 256, 0, stream>>>(gacc, b2, A1, ba1, A2, ba2, C1, bc1, C2, bc2, (float*)d_out);
}

// Round 17
// 186.321 us; speedup vs baseline: 1.1633x; 1.0036x over previous
//
#include <hip/hip_runtime.h>
#include <hip/hip_fp16.h>

#define NN 100000
#define NE 800000
#define NZB (NN / 32)          // 3125 zpool blocks
#define SRCMASK 0x01FFFFFF

typedef short bf16x8 __attribute__((ext_vector_type(8)));
typedef float f32x4 __attribute__((ext_vector_type(4)));

__device__ __forceinline__ float wave_reduce_sum(float v) {
    #pragma unroll
    for (int o = 32; o > 0; o >>= 1) v += __shfl_down(v, o, 64);
    return v; // valid in lane 0
}

__device__ __forceinline__ unsigned short f2bf(float f) {
    unsigned u = __float_as_uint(f);
    unsigned r = (u + 0x7FFFu + ((u >> 16) & 1u)) >> 16;
    return (unsigned short)r;
}
__device__ __forceinline__ float bf2f(unsigned short b) {
    return __uint_as_float(((unsigned)b) << 16);
}
__device__ __forceinline__ float bflo(unsigned u) {   // low bf16 of u32
    return __uint_as_float(u << 16);
}
__device__ __forceinline__ float bfhi(unsigned u) {   // high bf16 of u32
    return __uint_as_float(u & 0xFFFF0000u);
}
__device__ __forceinline__ unsigned pk2(float a, float b) {
    return (unsigned)f2bf(a) | ((unsigned)f2bf(b) << 16);
}
// fp8 e4m3fn via fp16-scale trick
__device__ __forceinline__ unsigned char f2fp8(float f) {
    __half h = __float2half(f * 0.00390625f);   // /256, RTNE
    unsigned short b = __half_as_ushort(h);
    unsigned s = (b >> 8) & 0x80u;
    unsigned mag = b & 0x7FFFu;
    mag = (mag + 0x3Fu + ((mag >> 7) & 1u)) >> 7;  // RTNE to 8-bit em
    if (mag > 0x7Eu) mag = 0x7Eu;                   // clamp (max 448, avoid NaN)
    return (unsigned char)(s | mag);
}
__device__ __forceinline__ float dfp8(unsigned v) {
    unsigned short hb = (unsigned short)(((v & 0x80u) << 8) | ((v & 0x7Fu) << 7));
    return __half2float(__ushort_as_half(hb)) * 256.f;
}

// cb layout (floats): [0..27] vs1(k*4+h)  [28..55] vd1  [56..59] c1[h]  [60] c2
// W2fr: 5 col-tiles x 8 k-slices, B-fragment order; tile ct=4 col0=W2@as2, col1=W2@ad2
__global__ void k_pre(const float* __restrict__ W1, const float* __restrict__ as1,
                      const float* __restrict__ ad1,
                      const float* __restrict__ We1, const float* __restrict__ ae1,
                      const float* __restrict__ We2, const float* __restrict__ ae2,
                      const float* __restrict__ W2, const float* __restrict__ as2,
                      const float* __restrict__ ad2,
                      float* __restrict__ cb, unsigned short* __restrict__ W2fr) {
    int t = threadIdx.x;
    if (blockIdx.x == 0) {
        if (t < 28) {
            int k = t >> 2, h = t & 3;
            float s = 0.f, d = 0.f;
            for (int c = 0; c < 64; ++c) {
                float w = W1[k * 256 + h * 64 + c];
                s += w * as1[h * 64 + c];
                d += w * ad1[h * 64 + c];
            }
            cb[t] = s; cb[28 + t] = d;
        } else if (t < 32) {
            int h = t - 28;
            float s = 0.f;
            for (int c = 0; c < 64; ++c) s += We1[h * 64 + c] * ae1[h * 64 + c];
            cb[56 + h] = s;
        } else if (t == 32) {
            float s = 0.f;
            for (int c = 0; c < 64; ++c) s += We2[c] * ae2[c];
            cb[60] = s;
        }
    } else {
        int o = (blockIdx.x - 1) * 256 + t;        // 0..20479
        if (o >= 20480) return;
        int i = o & 7, l = (o >> 3) & 63, rest = o >> 9;
        int ct = rest % 5, ks = rest / 5;
        int k = ks * 32 + ((l >> 4) * 8) + i;
        int cl = l & 15;
        if (ct < 4) {
            W2fr[o] = f2bf(W2[k * 64 + ct * 16 + cl]);
        } else if (cl < 2) {
            const float* av = (cl == 0) ? as2 : ad2;
            float s = 0.f;
            for (int j = 0; j < 64; ++j) s += W2[k * 64 + j] * av[j];
            W2fr[o] = f2bf(s);
        } else {
            W2fr[o] = 0;
        }
    }
}

// per-node: packed bf16 attention record + packed bf16 x-record;
// fused dst histogram capturing per-edge rank (coalesced int4 stores)
__global__ void k_node1h(const float* __restrict__ x, const float* __restrict__ cb,
                         const int* __restrict__ dst,
                         uint4* __restrict__ anode, uint4* __restrict__ xpack,
                         int* __restrict__ hist, int* __restrict__ rank) {
    int n = blockIdx.x * 256 + threadIdx.x;
    if (n >= NN) return;
    float xv[7];
    #pragma unroll
    for (int k = 0; k < 7; ++k) xv[k] = x[n * 7 + k];
    float s[4] = {0.f, 0.f, 0.f, 0.f}, d[4] = {0.f, 0.f, 0.f, 0.f};
    #pragma unroll
    for (int k = 0; k < 7; ++k)
        #pragma unroll
        for (int h = 0; h < 4; ++h) {
            s[h] += xv[k] * cb[k * 4 + h];
            d[h] += xv[k] * cb[28 + k * 4 + h];
        }
    anode[n] = make_uint4(pk2(s[0], s[1]), pk2(s[2], s[3]), pk2(d[0], d[1]), pk2(d[2], d[3]));
    xpack[n] = make_uint4(pk2(xv[0], xv[1]), pk2(xv[2], xv[3]),
                          pk2(xv[4], xv[5]), pk2(xv[6], 1.f));
    // histogram + rank: edges [n*8, n*8+8)
    int e0 = n * 8;
    int4 d0 = *(const int4*)(dst + e0);
    int4 d1 = *(const int4*)(dst + e0 + 4);
    int4 r0, r1;
    r0.x = atomicAdd(&hist[d0.x], 1); r0.y = atomicAdd(&hist[d0.y], 1);
    r0.z = atomicAdd(&hist[d0.z], 1); r0.w = atomicAdd(&hist[d0.w], 1);
    r1.x = atomicAdd(&hist[d1.x], 1); r1.y = atomicAdd(&hist[d1.y], 1);
    r1.z = atomicAdd(&hist[d1.z], 1); r1.w = atomicAdd(&hist[d1.w], 1);
    *(int4*)(rank + e0) = r0;
    *(int4*)(rank + e0 + 4) = r1;
}

// --- 3-phase parallel exclusive scan over hist[NN] -> offs[NN+1] ---
__global__ __launch_bounds__(1024) void k_scanA(const int* __restrict__ hist,
                                                int* __restrict__ bsum) {
    __shared__ int ws[16];
    int i = blockIdx.x * 1024 + threadIdx.x;
    int lane = threadIdx.x & 63, wid = threadIdx.x >> 6;
    int v = (i < NN) ? hist[i] : 0;
    #pragma unroll
    for (int o = 32; o; o >>= 1) v += __shfl_down(v, o, 64);
    if (lane == 0) ws[wid] = v;
    __syncthreads();
    if (wid == 0) {
        int u = (lane < 16) ? ws[lane] : 0;
        #pragma unroll
        for (int o = 8; o; o >>= 1) u += __shfl_down(u, o, 64);
        if (lane == 0) bsum[blockIdx.x] = u;
    }
}

__global__ void k_scanB(const int* __restrict__ bsum, int* __restrict__ bexcl) {
    __shared__ int w0tot;
    int t = threadIdx.x, lane = t & 63, wid = t >> 6;
    int v = (t < 98) ? bsum[t] : 0;
    int s = v;
    #pragma unroll
    for (int d = 1; d < 64; d <<= 1) { int u = __shfl_up(s, d, 64); if (lane >= d) s += u; }
    if (t == 63) w0tot = s;
    __syncthreads();
    if (wid == 1) s += w0tot;
    if (t < 98) bexcl[t] = s - v;
}

__global__ __launch_bounds__(1024) void k_scanC(const int* __restrict__ hist,
                                                const int* __restrict__ bexcl,
                                                int* __restrict__ offs) {
    __shared__ int ws[16];
    int b = blockIdx.x;
    int i = b * 1024 + threadIdx.x;
    int lane = threadIdx.x & 63, wid = threadIdx.x >> 6;
    int v = (i < NN) ? hist[i] : 0;
    int s = v;
    #pragma unroll
    for (int d = 1; d < 64; d <<= 1) { int u = __shfl_up(s, d, 64); if (lane >= d) s += u; }
    if (lane == 63) ws[wid] = s;
    __syncthreads();
    if (wid == 0) {
        int u2 = (lane < 16) ? ws[lane] : 0;
        #pragma unroll
        for (int d = 1; d < 16; d <<= 1) { int uu = __shfl_up(u2, d, 64); if (lane >= d) u2 += uu; }
        if (lane < 16) ws[lane] = u2;
    }
    __syncthreads();
    int incl = s + (wid ? ws[wid - 1] : 0) + bexcl[b];
    if (i < NN) offs[i + 1] = incl;
    if (i == 0) offs[0] = 0;
}

// scatter + conv1 edge weights; atomic-free (pos = offs[dst] + rank); 2 edges/thread
__global__ void k_scatter(const int* __restrict__ src, const int* __restrict__ dst,
                          const float* __restrict__ ea, const int* __restrict__ rank,
                          const int* __restrict__ offs,
                          const uint4* __restrict__ anode, const float* __restrict__ cb,
                          int4* __restrict__ es2) {
    int e0 = (blockIdx.x * 256 + threadIdx.x) * 2;
    if (e0 >= NE) return;
    int2 s2 = *(const int2*)(src + e0);
    int2 d2 = *(const int2*)(dst + e0);
    float2 a2 = *(const float2*)(ea + e0);
    int2 r2 = *(const int2*)(rank + e0);
    float c56 = cb[56], c57 = cb[57], c58 = cb[58], c59 = cb[59];
    #pragma unroll
    for (int u = 0; u < 2; ++u) {
        int s = u ? s2.y : s2.x;
        int d = u ? d2.y : d2.x;
        float eav = u ? a2.y : a2.x;
        int pos = offs[d] + (u ? r2.y : r2.x);
        uint4 ar = anode[s];
        uint4 br = anode[d];
        float lg0 = bflo(ar.x) + bflo(br.z) + eav * c56;
        float lg1 = bfhi(ar.x) + bfhi(br.z) + eav * c57;
        float lg2 = bflo(ar.y) + bflo(br.w) + eav * c58;
        float lg3 = bfhi(ar.y) + bfhi(br.w) + eav * c59;
        lg0 = lg0 >= 0.f ? lg0 : 0.2f * lg0;
        lg1 = lg1 >= 0.f ? lg1 : 0.2f * lg1;
        lg2 = lg2 >= 0.f ? lg2 : 0.2f * lg2;
        lg3 = lg3 >= 0.f ? lg3 : 0.2f * lg3;
        unsigned w01 = pk2(__expf(lg0), __expf(lg1));
        unsigned w23 = pk2(__expf(lg2), __expf(lg3));
        es2[pos] = make_int4((int)w01, (int)w23, s | ((d & 31) << 25), __float_as_int(eav));
    }
}

// fused conv1: packed-LDS two-phase segmented reduce -> h -> MFMA
// 5th col-tile computes a_src2/a_dst2 directly; xh2 stored fp8 e4m3
__global__ __launch_bounds__(256, 7) void k_conv1red(
    const uint4* __restrict__ xpack, const float* __restrict__ W1, const float* __restrict__ b1,
    const int* __restrict__ offs, const int4* __restrict__ es2,
    const unsigned short* __restrict__ W2fr,
    unsigned char* __restrict__ xh2f, float* __restrict__ a_src2, float* __restrict__ a_dst2) {
    // overlay: xs/wsx (phases 1-2) share storage with hs (finish/MFMA phases)
    __shared__ __attribute__((aligned(16))) unsigned char smem[16896];
    uint4* xs = (uint4*)smem;                                   // [256] 4096 B
    uint2* wsx = (uint2*)(smem + 4096);                         // [256] 2048 B
    typedef unsigned short hsrow[264];
    hsrow* hs = (hsrow*)smem;                                   // [32][264] 16896 B
    __shared__ int soffs[33];
    __shared__ float ms[32][33];
    int t = threadIdx.x, lane = t & 63, wid = t >> 6;
    int n0 = blockIdx.x * 32;
    if (t <= 32) soffs[t] = offs[n0 + t];
    float w1r[7][4], b1r[4];
    #pragma unroll
    for (int k = 0; k < 7; ++k)
        #pragma unroll
        for (int h = 0; h < 4; ++h) w1r[k][h] = W1[k * 256 + h * 64 + lane];
    #pragma unroll
    for (int h = 0; h < 4; ++h) b1r[h] = b1[h * 64 + lane];
    __syncthreads();
    int E0 = soffs[0], E1 = soffs[32];
    int g = t >> 3, q = t & 7;
    int go0 = soffs[g], go1 = soffs[g + 1];
    int qh = q >> 1;
    int xsl = (q & 1) ? 0 : 16;    // shift to put selected bf16 in high half
    float mh0 = 0.f, mh1 = 0.f, mh2 = 0.f, mh3 = 0.f;
    for (int C0 = E0; C0 < E1; C0 += 256) {
        int C1 = min(C0 + 256, E1);
        int j = C0 + t;
        if (j < C1) {
            int4 e4 = es2[j];
            xs[t] = xpack[e4.z & SRCMASK];
            wsx[t] = make_uint2((unsigned)e4.x, (unsigned)e4.y);
        }
        __syncthreads();
        int lo = max(go0, C0) - C0, hi = min(go1, C1) - C0;
        for (int jj = lo; jj < hi; ++jj) {
            unsigned xu = ((const unsigned*)&xs[jj])[qh];
            float xv = __uint_as_float((xu << xsl) & 0xFFFF0000u);
            uint2 wv = wsx[jj];
            mh0 = fmaf(bflo(wv.x), xv, mh0);
            mh1 = fmaf(bfhi(wv.x), xv, mh1);
            mh2 = fmaf(bflo(wv.y), xv, mh2);
            mh3 = fmaf(bfhi(wv.y), xv, mh3);
        }
        __syncthreads();
    }
    ms[g][0 * 8 + q] = mh0; ms[g][1 * 8 + q] = mh1;
    ms[g][2 * 8 + q] = mh2; ms[g][3 * 8 + q] = mh3;
    __syncthreads();          // xs/wsx dead from here; hs may now overwrite
    // finish: 8 nodes per wave, lane = channel
    for (int gi = wid * 8; gi < wid * 8 + 8; ++gi) {
        bool has = soffs[gi + 1] > soffs[gi];
        #pragma unroll
        for (int h = 0; h < 4; ++h) {
            float rz = __builtin_amdgcn_rcpf(ms[gi][h * 8 + 7]);
            float a = 0.f;
            #pragma unroll
            for (int k = 0; k < 7; ++k) a = fmaf(ms[gi][h * 8 + k], w1r[k][h], a);
            float mm = (has ? a * rz : 0.f) + b1r[h];
            float hv = mm > 0.f ? mm : (__expf(mm) - 1.f);
            hs[gi][h * 64 + lane] = f2bf(hv);
        }
    }
    __syncthreads();
    // MFMA: 2 node-tiles x 5 col-tiles (ct=4 -> a_src2/a_dst2 columns)
    int row = lane & 15, kg = lane >> 4;
    #pragma unroll
    for (int u = wid; u < 10; u += 4) {
        int nt = u & 1, ct = u >> 1;
        f32x4 acc = {0.f, 0.f, 0.f, 0.f};
        #pragma unroll
        for (int ks = 0; ks < 8; ++ks) {
            bf16x8 av = *(const bf16x8*)&hs[nt * 16 + row][ks * 32 + kg * 8];
            bf16x8 bv = *(const bf16x8*)(W2fr + (((ks * 5 + ct) * 64) + lane) * 8);
            acc = __builtin_amdgcn_mfma_f32_16x16x32_bf16(av, bv, acc, 0, 0, 0);
        }
        if (ct < 4) {
            #pragma unroll
            for (int i = 0; i < 4; ++i)
                xh2f[(n0 + nt * 16 + kg * 4 + i) * 64 + ct * 16 + row] = f2fp8(acc[i]);
        } else if (row == 0) {
            #pragma unroll
            for (int i = 0; i < 4; ++i) a_src2[n0 + nt * 16 + kg * 4 + i] = acc[i];
        } else if (row == 1) {
            #pragma unroll
            for (int i = 0; i < 4; ++i) a_dst2[n0 + nt * 16 + kg * 4 + i] = acc[i];
        }
    }
}

// conv2 normalization + fused cluster pooling (no global atomics), fp8 V-side:
__global__ __launch_bounds__(256) void k_zpool(
    const int4* __restrict__ es2, const int* __restrict__ offs,
    const float* __restrict__ a_src2, const float* __restrict__ a_dst2,
    const int* __restrict__ assign, const float* __restrict__ cb,
    const unsigned char* __restrict__ xh2f, const float* __restrict__ x,
    float* __restrict__ partial) {
    __shared__ int soffs[33];
    __shared__ float adL[32];
    __shared__ int asgL[32];
    __shared__ float ewL[512];
    __shared__ int sL[512];
    __shared__ float rzL[32];
    __shared__ float zacc[32];
    __shared__ float csum[264];
    int t = threadIdx.x;
    int n0 = blockIdx.x * 32;
    if (t <= 32) soffs[t] = offs[n0 + t];
    if (t < 32) { adL[t] = a_dst2[n0 + t]; asgL[t] = assign[n0 + t]; zacc[t] = 0.f; }
    for (int i = t; i < 264; i += 256) csum[i] = 0.f;
    __syncthreads();
    int E0 = soffs[0], E1 = soffs[32];
    float c2 = cb[60];
    if (E0 + t < E1) {
        int4 e4 = es2[E0 + t];
        int sx = e4.z & SRCMASK;
        int d5 = (e4.z >> 25) & 31;
        float lg = a_src2[sx] + adL[d5] + __int_as_float(e4.w) * c2;
        lg = lg >= 0.f ? lg : 0.2f * lg;
        ewL[t] = __expf(lg);
        sL[t] = sx;
    }
    if (E0 + 256 + t < E1) {
        int4 e4 = es2[E0 + 256 + t];
        int sx = e4.z & SRCMASK;
        int d5 = (e4.z >> 25) & 31;
        float lg = a_src2[sx] + adL[d5] + __int_as_float(e4.w) * c2;
        lg = lg >= 0.f ? lg : 0.2f * lg;
        ewL[256 + t] = __expf(lg);
        sL[256 + t] = sx;
    }
    // rare overflow edges: accumulate z via LDS atomics
    for (int j = E0 + 512 + t; j < E1; j += 256) {
        int4 e4 = es2[j];
        int d5 = (e4.z >> 25) & 31;
        float lg = a_src2[e4.z & SRCMASK] + adL[d5] + __int_as_float(e4.w) * c2;
        lg = lg >= 0.f ? lg : 0.2f * lg;
        atomicAdd(&zacc[d5], __expf(lg));
    }
    __syncthreads();
    // per-node z from ewL (8 lanes per node)
    int g = t >> 3, q = t & 7;
    int lo = soffs[g] - E0, hi = soffs[g + 1] - E0;
    int hicap = min(hi, 512);
    float z = 0.f;
    for (int jj = lo + q; jj < hicap; jj += 8) z += ewL[jj];
    z += __shfl_xor(z, 1, 64);
    z += __shfl_xor(z, 2, 64);
    z += __shfl_xor(z, 4, 64);
    if (q == 0) rzL[g] = __builtin_amdgcn_rcpf(z + zacc[g]);
    __syncthreads();
    // pass 2: gather fp8 xh2 rows (64B/row = 1 line), accumulate weighted into regs
    float rzv = rzL[g];
    float a0 = 0.f, a1 = 0.f, a2 = 0.f, a3 = 0.f;
    float a4 = 0.f, a5 = 0.f, a6 = 0.f, a7 = 0.f;
    for (int jj = lo; jj < hicap; ++jj) {
        float wv = ewL[jj] * rzv;
        int sj = sL[jj];
        uint2 u = *(const uint2*)(xh2f + sj * 64 + q * 8);
        a0 = fmaf(wv, dfp8(u.x & 255u), a0);
        a1 = fmaf(wv, dfp8((u.x >> 8) & 255u), a1);
        a2 = fmaf(wv, dfp8((u.x >> 16) & 255u), a2);
        a3 = fmaf(wv, dfp8(u.x >> 24), a3);
        a4 = fmaf(wv, dfp8(u.y & 255u), a4);
        a5 = fmaf(wv, dfp8((u.y >> 8) & 255u), a5);
        a6 = fmaf(wv, dfp8((u.y >> 16) & 255u), a6);
        a7 = fmaf(wv, dfp8(u.y >> 24), a7);
    }
    // rare overflow edges (recompute ew)
    for (int jo = max(lo, 512); jo < hi; ++jo) {
        int4 e4 = es2[E0 + jo];
        int sx = e4.z & SRCMASK;
        float lg = a_src2[sx] + adL[g] + __int_as_float(e4.w) * c2;
        lg = lg >= 0.f ? lg : 0.2f * lg;
        float wv = __expf(lg) * rzv;
        uint2 u = *(const uint2*)(xh2f + sx * 64 + q * 8);
        a0 = fmaf(wv, dfp8(u.x & 255u), a0);
        a1 = fmaf(wv, dfp8((u.x >> 8) & 255u), a1);
        a2 = fmaf(wv, dfp8((u.x >> 16) & 255u), a2);
        a3 = fmaf(wv, dfp8(u.x >> 24), a3);
        a4 = fmaf(wv, dfp8(u.y & 255u), a4);
        a5 = fmaf(wv, dfp8((u.y >> 8) & 255u), a5);
        a6 = fmaf(wv, dfp8((u.y >> 16) & 255u), a6);
        a7 = fmaf(wv, dfp8(u.y >> 24), a7);
    }
    int cb_ = asgL[g] * 64 + q * 8;
    atomicAdd(&csum[cb_ + 0], a0); atomicAdd(&csum[cb_ + 1], a1);
    atomicAdd(&csum[cb_ + 2], a2); atomicAdd(&csum[cb_ + 3], a3);
    atomicAdd(&csum[cb_ + 4], a4); atomicAdd(&csum[cb_ + 5], a5);
    atomicAdd(&csum[cb_ + 6], a6); atomicAdd(&csum[cb_ + 7], a7);
    if (t < 32) {
        int c = asgL[t];
        atomicAdd(&csum[256 + c], 1.f);
        atomicAdd(&csum[260 + c], x[(n0 + t) * 7 + 6]);
    }
    __syncthreads();
    for (int i = t; i < 264; i += 256) partial[blockIdx.x * 264 + i] = csum[i];
}

// reduce partials -> gacc[264]
__global__ void k_red(const float* __restrict__ partial, float* __restrict__ gacc) {
    int i = blockIdx.x;   // 264 blocks x 64 threads
    float s = 0.f;
    for (int b = threadIdx.x; b < NZB; b += 64) s += partial[b * 264 + i];
    s = wave_reduce_sum(s);
    if (threadIdx.x == 0) gacc[i] = s;
}

// final head (256 threads): cluster means (+cnt*b2), actor MLP + softmax, critic MLP
__global__ __launch_bounds__(256) void k_head(
    const float* __restrict__ gacc, const float* __restrict__ b2,
    const float* __restrict__ A1, const float* __restrict__ ba1,
    const float* __restrict__ A2, const float* __restrict__ ba2,
    const float* __restrict__ C1, const float* __restrict__ bc1,
    const float* __restrict__ C2, const float* __restrict__ bc2,
    float* __restrict__ out) {
    __shared__ float zc[4][64];
    __shared__ float cfs[4];
    __shared__ float logits[4];
    __shared__ float vpart[4][64];
    int t = threadIdx.x;
    int j = t & 63, wv = t >> 6;   // wave wv handles cluster wv
    float cnt = gacc[256 + wv];
    float den = fmaxf(cnt, 1.f);
    zc[wv][j] = (cnt > 0.f) ? (gacc[wv * 64 + j] + cnt * b2[j]) / den : 0.f;
    if (t < 4) {
        float cc = gacc[256 + t];
        cfs[t] = (cc > 0.f) ? gacc[260 + t] / fmaxf(cc, 1.f) : 0.f;
    }
    __syncthreads();
    // actor: cluster wv
    float tv = ba1[j];
    for (int k = 0; k < 64; ++k) tv = fmaf(zc[wv][k], A1[k * 64 + j], tv);
    tv = fmaf(cfs[wv], A1[64 * 64 + j], tv);
    tv = fmaxf(tv, 0.f);
    float sred = wave_reduce_sum(tv * A2[j]);
    if (j == 0) logits[wv] = sred + ba2[0];
    // critic partials: wave wv covers k in [wv*64, (wv+1)*64)
    float vj = (wv == 0) ? bc1[j] : 0.f;
    for (int kk = 0; kk < 64; ++kk) vj = fmaf(zc[wv][kk], C1[(wv * 64 + kk) * 64 + j], vj);
    vpart[wv][j] = vj;
    __syncthreads();
    if (wv == 0) {
        float vv = fmaxf(vpart[0][j] + vpart[1][j] + vpart[2][j] + vpart[3][j], 0.f);
        float v = wave_reduce_sum(vv * C2[j]);
        if (j == 0) {
            float m = fmaxf(fmaxf(logits[0], logits[1]), fmaxf(logits[2], logits[3]));
            float e0 = __expf(logits[0] - m), e1 = __expf(logits[1] - m);
            float e2 = __expf(logits[2] - m), e3 = __expf(logits[3] - m);
            float sum = e0 + e1 + e2 + e3;
            out[0] = e0 / sum; out[1] = e1 / sum; out[2] = e2 / sum; out[3] = e3 / sum;
            out[4] = v + bc2[0];
        }
    }
    out[5 + wv * 64 + j] = zc[wv][j];
}

extern "C" void kernel_launch(void* const* d_in, const int* in_sizes, int n_in,
                              void* d_out, int out_size, void* d_ws, size_t ws_size,
                              hipStream_t stream) {
    const float* x    = (const float*)d_in[0];
    const int*   ei   = (const int*)d_in[1];
    const float* ea   = (const float*)d_in[2];
    const int*   asg  = (const int*)d_in[3];
    const float* W1   = (const float*)d_in[4];
    const float* as1  = (const float*)d_in[5];
    const float* ad1  = (const float*)d_in[6];
    const float* We1  = (const float*)d_in[7];
    const float* ae1  = (const float*)d_in[8];
    const float* b1   = (const float*)d_in[9];
    const float* W2   = (const float*)d_in[10];
    const float* as2  = (const float*)d_in[11];
    const float* ad2  = (const float*)d_in[12];
    const float* We2  = (const float*)d_in[13];
    const float* ae2  = (const float*)d_in[14];
    const float* b2   = (const float*)d_in[15];
    const float* A1   = (const float*)d_in[16];
    const float* ba1  = (const float*)d_in[17];
    const float* A2   = (const float*)d_in[18];
    const float* ba2  = (const float*)d_in[19];
    const float* C1   = (const float*)d_in[20];
    const float* bc1  = (const float*)d_in[21];
    const float* C2   = (const float*)d_in[22];
    const float* bc2  = (const float*)d_in[23];
    const int* src = ei;
    const int* dst = ei + NE;

    char* w = (char*)d_ws;
    size_t off = 0;
    auto alloc = [&](size_t bytes) -> void* {
        void* p = w + off;
        off += (bytes + 255) & ~(size_t)255;
        return p;
    };
    int*   hist   = (int*)alloc(NN * sizeof(int));
    float* gacc   = (float*)alloc(264 * sizeof(float));
    float* partial= (float*)alloc((size_t)NZB * 264 * sizeof(float));
    uint4* anode  = (uint4*)alloc(NN * sizeof(uint4));
    float* a_src2 = (float*)alloc(NN * sizeof(float));
    float* a_dst2 = (float*)alloc(NN * sizeof(float));
    uint4* xpack  = (uint4*)alloc(NN * sizeof(uint4));
    int*   offs   = (int*)alloc((NN + 1) * sizeof(int));
    int*   rank   = (int*)alloc(NE * sizeof(int));
    int*   bsum   = (int*)alloc(128 * sizeof(int));
    int*   bexcl  = (int*)alloc(128 * sizeof(int));
    int4*  es2    = (int4*)alloc(NE * sizeof(int4));
    unsigned char* xh2f = (unsigned char*)alloc(NN * 64 * sizeof(unsigned char));
    unsigned short* W2fr = (unsigned short*)alloc(20480 * sizeof(unsigned short));
    float* cb     = (float*)alloc(64 * sizeof(float));
    (void)ws_size; (void)n_in; (void)in_sizes; (void)out_size;

    (void)hipMemsetAsync(hist, 0, NN * sizeof(int), stream);

    k_pre<<<81, 256, 0, stream>>>(W1, as1, ad1, We1, ae1, We2, ae2, W2, as2, ad2, cb, W2fr);
    k_node1h<<<(NN + 255) / 256, 256, 0, stream>>>(x, cb, dst, anode, xpack, hist, rank);
    k_scanA<<<98, 1024, 0, stream>>>(hist, bsum);
    k_scanB<<<1, 128, 0, stream>>>(bsum, bexcl);
    k_scanC<<<98, 1024, 0, stream>>>(hist, bexcl, offs);
    k_scatter<<<(NE / 2 + 255) / 256, 256, 0, stream>>>(src, dst, ea, rank, offs,
                                                        anode, cb, es2);
    k_conv1red<<<NN / 32, 256, 0, stream>>>(xpack, W1, b1, offs, es2,
                                            W2fr, xh2f, a_src2, a_dst2);
    k_zpool<<<NZB, 256, 0, stream>>>(es2, offs, a_src2, a_dst2, asg, cb, xh2f, x, partial);
    k_red<<<264, 64, 0, stream>>>(partial, gacc);
    k_head<<<1, 256, 0, stream>>>(gacc, b2, A1, ba1, A2, ba2, C1, bc1, C2, bc2, (float*)d_out);
}